// Round 10
// baseline (234.051 us; speedup 1.0000x reference)
//
#include <hip/hip_runtime.h>
#include <hip/hip_bf16.h>

// DeltaNet chunkwise delta rule, b=2 h=8 L=4096 dk=dv=128 chunk=32.
// Phase2 (2048 wgs x 64 thr): EXACT round-3 stream (56us; r4-r8 proved every
//   variation regresses it).
// Phase3 = two-level scan over S' = (I - k^T w) S + k^T u, 16 groups x 8
//   chunks, XCD-L2 sharing via block swizzle (round-3).
//   Phase3b (r9): 4-wave cooperative serial propagation (proven -5us).
//   Round-10: phase3c -> 2-wave cooperative (128 thr): wave ww owns accS
//   mt 4ww..4ww+3, accU/accO[mt2=ww], half the frag loads; 2 barriers/step.
//   Occupancy 8->16 waves/CU, per-block serial latency ~halves.
//   Bit-identical numerics (same per-element MFMA order).

#define B 2
#define H 8
#define LSEQ 4096
#define DK 128
#define DV 128
#define C 32
#define NCHUNK (LSEQ / C)      // 128
#define BH (B * H)             // 16
#define NBLK (BH * NCHUNK)     // 2048
#define NG 16                  // groups
#define GSZ 8                  // chunks per group (NG*GSZ == NCHUNK)

typedef _Float16 f16x8 __attribute__((ext_vector_type(8)));
typedef float f32x4 __attribute__((ext_vector_type(4)));

union U4H8 { uint4 u; f16x8 h; };

__device__ inline unsigned short f2h(float f) {
    _Float16 h = (_Float16)f;
    unsigned short u;
    __builtin_memcpy(&u, &h, 2);
    return u;
}
__device__ inline float h2f(unsigned int v) {
    unsigned short s = (unsigned short)v;
    _Float16 h;
    __builtin_memcpy(&h, &s, 2);
    return (float)h;
}
__device__ inline unsigned int pack2(float a, float b) {
    return (unsigned int)f2h(a) | ((unsigned int)f2h(b) << 16);
}
__device__ inline float dot4(float4 a, float4 b) {
    return a.x * b.x + a.y * b.y + a.z * b.z + a.w * b.w;
}
__device__ inline float bf16r(float x) {
    return __bfloat162float(__float2bfloat16(x));
}
__device__ inline uint2 pk4(float v0, float v1, float v2, float v3) {
    uint2 p; p.x = pack2(v0, v1); p.y = pack2(v2, v3); return p;
}
__device__ inline f32x4 up4(uint2 p) {
    f32x4 v;
    v[0] = h2f(p.x & 0xffffu); v[1] = h2f(p.x >> 16);
    v[2] = h2f(p.y & 0xffffu); v[3] = h2f(p.y >> 16);
    return v;
}

// ---------------- Phase 2 (exact round-3) ----------------
#define S40 40
#define S136 136

__global__ __launch_bounds__(64) void phase2_kernel(
    const float* __restrict__ qg, const float* __restrict__ kg,
    const float* __restrict__ vg, const float* __restrict__ betag,
    uint4* __restrict__ wnegf, uint4* __restrict__ qnf,
    uint4* __restrict__ ktf, uint4* __restrict__ atf,
    uint2* __restrict__ uf)
{
    __shared__ alignas(16) _Float16 sA [32 * S40];
    __shared__ alignas(16) _Float16 sAT[32 * S40];
    __shared__ alignas(16) _Float16 sTT[32 * S40];
    __shared__ alignas(16) _Float16 sTB[32 * S40];
    __shared__ alignas(16) _Float16 sW [32 * S136];
    __shared__ alignas(16) float sbetaL[32];
    __shared__ alignas(16) float skscL[32];

    const int l = threadIdx.x;
    const int lm = l & 15, qd = l >> 4;
    const int blk = blockIdx.x;
    const long tb = (long)blk * C * DK;
    const f32x4 z4 = {0.f, 0.f, 0.f, 0.f};

    if (l < 32) sbetaL[l] = betag[(long)blk * C + l];

    U4H8 qF[8], kF[8];
    float ssq[2] = {0.f, 0.f}, ssk[2] = {0.f, 0.f};
    #pragma unroll
    for (int mt = 0; mt < 2; mt++) {
        #pragma unroll
        for (int kt = 0; kt < 4; kt++) {
            const float* qp = qg + tb + (long)(mt * 16 + lm) * DK + kt * 32 + qd * 8;
            const float* kp = kg + tb + (long)(mt * 16 + lm) * DK + kt * 32 + qd * 8;
            float4 a0 = *(const float4*)qp, a1 = *(const float4*)(qp + 4);
            float4 b0 = *(const float4*)kp, b1 = *(const float4*)(kp + 4);
            ssq[mt] += dot4(a0, a0) + dot4(a1, a1);
            ssk[mt] += dot4(b0, b0) + dot4(b1, b1);
            U4H8 x;
            x.u.x = pack2(a0.x, a0.y); x.u.y = pack2(a0.z, a0.w);
            x.u.z = pack2(a1.x, a1.y); x.u.w = pack2(a1.z, a1.w);
            qF[mt * 4 + kt] = x;
            U4H8 y;
            y.u.x = pack2(b0.x, b0.y); y.u.y = pack2(b0.z, b0.w);
            y.u.z = pack2(b1.x, b1.y); y.u.w = pack2(b1.z, b1.w);
            kF[mt * 4 + kt] = y;
        }
    }
    float qsc[2], ksc[2];
    #pragma unroll
    for (int mt = 0; mt < 2; mt++) {
        float s = ssq[mt];
        s += __shfl_xor(s, 16, 64);
        s += __shfl_xor(s, 32, 64);
        qsc[mt] = rsqrtf(s + 1e-6f);
        float t = ssk[mt];
        t += __shfl_xor(t, 16, 64);
        t += __shfl_xor(t, 32, 64);
        ksc[mt] = rsqrtf(t + 1e-6f);
    }
    if (qd == 0) { skscL[lm] = ksc[0]; skscL[16 + lm] = ksc[1]; }

    f32x4 alT[3] = {z4, z4, z4};
    #pragma unroll
    for (int kt = 0; kt < 4; kt++) {
        alT[0] = __builtin_amdgcn_mfma_f32_16x16x32_f16(kF[kt].h,     qF[kt].h,     alT[0], 0, 0, 0);
        alT[1] = __builtin_amdgcn_mfma_f32_16x16x32_f16(kF[kt].h,     qF[4 + kt].h, alT[1], 0, 0, 0);
        alT[2] = __builtin_amdgcn_mfma_f32_16x16x32_f16(kF[4 + kt].h, qF[4 + kt].h, alT[2], 0, 0, 0);
    }
    #pragma unroll
    for (int mt = 0; mt < 2; mt++) {
        _Float16 qs = (_Float16)qsc[mt];
        #pragma unroll
        for (int kt = 0; kt < 4; kt++) {
            U4H8 x;
            x.h = qF[mt * 4 + kt].h * qs;
            qnf[((long)blk * 8 + mt * 4 + kt) * 64 + l] = x.u;
        }
    }
    f32x4 rw[4] = {z4, z4, z4, z4};
    #pragma unroll
    for (int kt = 0; kt < 4; kt++) {
        rw[0] = __builtin_amdgcn_mfma_f32_16x16x32_f16(kF[kt].h,     kF[kt].h,     rw[0], 0, 0, 0);
        rw[1] = __builtin_amdgcn_mfma_f32_16x16x32_f16(kF[kt].h,     kF[4 + kt].h, rw[1], 0, 0, 0);
        rw[2] = __builtin_amdgcn_mfma_f32_16x16x32_f16(kF[4 + kt].h, kF[kt].h,     rw[2], 0, 0, 0);
        rw[3] = __builtin_amdgcn_mfma_f32_16x16x32_f16(kF[4 + kt].h, kF[4 + kt].h, rw[3], 0, 0, 0);
    }

    float4 b4[2], ks4[2];
    b4[0]  = *(const float4*)&sbetaL[qd * 4];      b4[1]  = *(const float4*)&sbetaL[16 + qd * 4];
    ks4[0] = *(const float4*)&skscL[qd * 4];       ks4[1] = *(const float4*)&skscL[16 + qd * 4];
    const float bcol0 = sbetaL[lm], bcol1 = sbetaL[16 + lm];

    {
        *(uint2*)&sTB[lm * S40 + 16 + qd * 4] = (uint2){0u, 0u};
        float v[4];
        #pragma unroll
        for (int r = 0; r < 4; r++) {
            int c = qd * 4 + r;
            v[r] = (c <= lm) ? (qsc[0] * (&ks4[0].x)[r] * alT[0][r]) : 0.f;
        }
        *(uint2*)&sTB[lm * S40 + qd * 4] = pk4(v[0], v[1], v[2], v[3]);
        #pragma unroll
        for (int r = 0; r < 4; r++) v[r] = qsc[1] * (&ks4[0].x)[r] * alT[1][r];
        *(uint2*)&sTB[(16 + lm) * S40 + qd * 4] = pk4(v[0], v[1], v[2], v[3]);
        #pragma unroll
        for (int r = 0; r < 4; r++) {
            int c = qd * 4 + r;
            v[r] = (c <= lm) ? (qsc[1] * (&ks4[1].x)[r] * alT[2][r]) : 0.f;
        }
        *(uint2*)&sTB[(16 + lm) * S40 + 16 + qd * 4] = pk4(v[0], v[1], v[2], v[3]);
    }
    #pragma unroll
    for (int f = 0; f < 2; f++) {
        uint4 x = *(const uint4*)&sTB[(f * 16 + lm) * S40 + qd * 8];
        atf[((long)blk * 2 + f) * 64 + l] = x;
    }

    {
        float v[4];
        *(uint2*)&sA [lm * S40 + 16 + qd * 4]        = (uint2){0u, 0u};
        *(uint2*)&sAT[(16 + lm) * S40 + qd * 4]      = (uint2){0u, 0u};
        *(uint2*)&sTT[(16 + lm) * S40 + qd * 4]      = (uint2){0u, 0u};
        #pragma unroll
        for (int r = 0; r < 4; r++) {
            int c = qd * 4 + r;
            v[r] = (c < lm) ? (-bcol0 * ksc[0] * (&ks4[0].x)[r] * rw[0][r]) : 0.f;
        }
        *(uint2*)&sA[lm * S40 + qd * 4] = pk4(v[0], v[1], v[2], v[3]);
        #pragma unroll
        for (int r = 0; r < 4; r++) v[r] = -bcol1 * ksc[1] * (&ks4[0].x)[r] * rw[1][r];
        *(uint2*)&sA[(16 + lm) * S40 + qd * 4] = pk4(v[0], v[1], v[2], v[3]);
        #pragma unroll
        for (int r = 0; r < 4; r++) {
            int c = qd * 4 + r;
            v[r] = (c < lm) ? (-bcol1 * ksc[1] * (&ks4[1].x)[r] * rw[3][r]) : 0.f;
        }
        *(uint2*)&sA[(16 + lm) * S40 + 16 + qd * 4] = pk4(v[0], v[1], v[2], v[3]);
        #pragma unroll
        for (int r = 0; r < 4; r++) {
            int c = qd * 4 + r;
            v[r] = (c > lm) ? (-(&b4[0].x)[r] * (&ks4[0].x)[r] * ksc[0] * rw[0][r]) : 0.f;
        }
        *(uint2*)&sAT[lm * S40 + qd * 4] = pk4(v[0], v[1], v[2], v[3]);
        #pragma unroll
        for (int r = 0; r < 4; r++) v[r] = -(&b4[1].x)[r] * (&ks4[1].x)[r] * ksc[0] * rw[2][r];
        *(uint2*)&sAT[lm * S40 + 16 + qd * 4] = pk4(v[0], v[1], v[2], v[3]);
        #pragma unroll
        for (int r = 0; r < 4; r++) {
            int c = qd * 4 + r;
            v[r] = (c > lm) ? (-(&b4[1].x)[r] * (&ks4[1].x)[r] * ksc[1] * rw[3][r]) : 0.f;
        }
        *(uint2*)&sAT[(16 + lm) * S40 + 16 + qd * 4] = pk4(v[0], v[1], v[2], v[3]);
        #pragma unroll
        for (int r = 0; r < 4; r++) {
            int c = qd * 4 + r;
            v[r] = (c > lm) ? (-(&b4[0].x)[r] * (&ks4[0].x)[r] * ksc[0] * rw[0][r])
                            : ((c == lm) ? 1.0f : 0.f);
        }
        *(uint2*)&sTT[lm * S40 + qd * 4] = pk4(v[0], v[1], v[2], v[3]);
        #pragma unroll
        for (int r = 0; r < 4; r++) v[r] = -(&b4[1].x)[r] * (&ks4[1].x)[r] * ksc[0] * rw[2][r];
        *(uint2*)&sTT[lm * S40 + 16 + qd * 4] = pk4(v[0], v[1], v[2], v[3]);
        #pragma unroll
        for (int r = 0; r < 4; r++) {
            int c = qd * 4 + r;
            v[r] = (c > lm) ? (-(&b4[1].x)[r] * (&ks4[1].x)[r] * ksc[1] * rw[3][r])
                            : ((c == lm) ? 1.0f : 0.f);
        }
        *(uint2*)&sTT[(16 + lm) * S40 + 16 + qd * 4] = pk4(v[0], v[1], v[2], v[3]);
    }
    f32x4 Tc[3], TTc[3];
    #pragma unroll
    for (int r = 0; r < 4; r++) {
        int rr = qd * 4 + r;
        Tc[0][r] = (lm < rr) ? (-(&b4[0].x)[r] * (&ks4[0].x)[r] * ksc[0] * rw[0][r])
                             : ((lm == rr) ? 1.0f : 0.f);
        Tc[1][r] = -(&b4[1].x)[r] * (&ks4[1].x)[r] * ksc[0] * rw[2][r];
        Tc[2][r] = (lm < rr) ? (-(&b4[1].x)[r] * (&ks4[1].x)[r] * ksc[1] * rw[3][r])
                             : ((lm == rr) ? 1.0f : 0.f);
        TTc[0][r] = (rr < lm) ? (-bcol0 * ksc[0] * (&ks4[0].x)[r] * rw[0][r])
                              : ((rr == lm) ? 1.0f : 0.f);
        TTc[1][r] = -bcol1 * ksc[1] * (&ks4[0].x)[r] * rw[1][r];
        TTc[2][r] = (rr < lm) ? (-bcol1 * ksc[1] * (&ks4[1].x)[r] * rw[3][r])
                              : ((rr == lm) ? 1.0f : 0.f);
    }

    #pragma unroll
    for (int p = 0; p < 4; p++) {
        U4H8 AF[2], ATF[2], TTF[2];
        AF[0].u  = *(const uint4*)&sA [lm * S40 + qd * 8];
        AF[1].u  = *(const uint4*)&sA [(16 + lm) * S40 + qd * 8];
        ATF[0].u = *(const uint4*)&sAT[lm * S40 + qd * 8];
        ATF[1].u = *(const uint4*)&sAT[(16 + lm) * S40 + qd * 8];
        TTF[0].u = *(const uint4*)&sTT[lm * S40 + qd * 8];
        TTF[1].u = *(const uint4*)&sTT[(16 + lm) * S40 + qd * 8];

        f32x4 A2_00 = __builtin_amdgcn_mfma_f32_16x16x32_f16(AF[0].h, ATF[0].h, z4, 0, 0, 0);
        f32x4 A2_10 = __builtin_amdgcn_mfma_f32_16x16x32_f16(AF[1].h, ATF[0].h, z4, 0, 0, 0);
        f32x4 A2_11 = __builtin_amdgcn_mfma_f32_16x16x32_f16(AF[1].h, ATF[1].h, z4, 0, 0, 0);
        f32x4 A2T_00 = __builtin_amdgcn_mfma_f32_16x16x32_f16(ATF[0].h, AF[0].h, z4, 0, 0, 0);
        f32x4 A2T_01 = __builtin_amdgcn_mfma_f32_16x16x32_f16(ATF[0].h, AF[1].h, z4, 0, 0, 0);
        f32x4 A2T_11 = __builtin_amdgcn_mfma_f32_16x16x32_f16(ATF[1].h, AF[1].h, z4, 0, 0, 0);

        {
            float v[4];
            #pragma unroll
            for (int r = 0; r < 4; r++) { int c = qd * 4 + r; v[r] = (c < lm) ? A2T_00[r] : 0.f; }
            *(uint2*)&sA[lm * S40 + qd * 4] = pk4(v[0], v[1], v[2], v[3]);
            *(uint2*)&sA[(16 + lm) * S40 + qd * 4] = pk4(A2T_01[0], A2T_01[1], A2T_01[2], A2T_01[3]);
            #pragma unroll
            for (int r = 0; r < 4; r++) { int c = qd * 4 + r; v[r] = (c < lm) ? A2T_11[r] : 0.f; }
            *(uint2*)&sA[(16 + lm) * S40 + 16 + qd * 4] = pk4(v[0], v[1], v[2], v[3]);
        }
        if (p < 3) {
            float v[4];
            #pragma unroll
            for (int r = 0; r < 4; r++) { int c = qd * 4 + r; v[r] = (c > lm) ? A2_00[r] : 0.f; }
            *(uint2*)&sAT[lm * S40 + qd * 4] = pk4(v[0], v[1], v[2], v[3]);
            *(uint2*)&sAT[lm * S40 + 16 + qd * 4] = pk4(A2_10[0], A2_10[1], A2_10[2], A2_10[3]);
            #pragma unroll
            for (int r = 0; r < 4; r++) { int c = qd * 4 + r; v[r] = (c > lm) ? A2_11[r] : 0.f; }
            *(uint2*)&sAT[(16 + lm) * S40 + 16 + qd * 4] = pk4(v[0], v[1], v[2], v[3]);
        }
        U4H8 AnF[2];
        AnF[0].u = *(const uint4*)&sA[lm * S40 + qd * 8];
        AnF[1].u = *(const uint4*)&sA[(16 + lm) * S40 + qd * 8];
        Tc[0]  = __builtin_amdgcn_mfma_f32_16x16x32_f16(AnF[0].h, TTF[0].h, Tc[0], 0, 0, 0);
        Tc[1]  = __builtin_amdgcn_mfma_f32_16x16x32_f16(AnF[1].h, TTF[0].h, Tc[1], 0, 0, 0);
        Tc[2]  = __builtin_amdgcn_mfma_f32_16x16x32_f16(AnF[1].h, TTF[1].h, Tc[2], 0, 0, 0);
        TTc[0] = __builtin_amdgcn_mfma_f32_16x16x32_f16(TTF[0].h, AnF[0].h, TTc[0], 0, 0, 0);
        TTc[1] = __builtin_amdgcn_mfma_f32_16x16x32_f16(TTF[0].h, AnF[1].h, TTc[1], 0, 0, 0);
        TTc[2] = __builtin_amdgcn_mfma_f32_16x16x32_f16(TTF[1].h, AnF[1].h, TTc[2], 0, 0, 0);
        if (p < 3) {
            *(uint2*)&sTT[lm * S40 + qd * 4]             = pk4(Tc[0][0], Tc[0][1], Tc[0][2], Tc[0][3]);
            *(uint2*)&sTT[lm * S40 + 16 + qd * 4]        = pk4(Tc[1][0], Tc[1][1], Tc[1][2], Tc[1][3]);
            *(uint2*)&sTT[(16 + lm) * S40 + 16 + qd * 4] = pk4(Tc[2][0], Tc[2][1], Tc[2][2], Tc[2][3]);
        }
    }

    {
        *(uint2*)&sTB[lm * S40 + 16 + qd * 4] = (uint2){0u, 0u};
        float v[4];
        #pragma unroll
        for (int r = 0; r < 4; r++) v[r] = bf16r(TTc[0][r]) * (&b4[0].x)[r];
        *(uint2*)&sTB[lm * S40 + qd * 4] = pk4(v[0], v[1], v[2], v[3]);
        #pragma unroll
        for (int r = 0; r < 4; r++) v[r] = bf16r(TTc[1][r]) * (&b4[0].x)[r];
        *(uint2*)&sTB[(16 + lm) * S40 + qd * 4] = pk4(v[0], v[1], v[2], v[3]);
        #pragma unroll
        for (int r = 0; r < 4; r++) v[r] = bf16r(TTc[2][r]) * (&b4[1].x)[r];
        *(uint2*)&sTB[(16 + lm) * S40 + 16 + qd * 4] = pk4(v[0], v[1], v[2], v[3]);
    }
    U4H8 TbF[2];
    TbF[0].u = *(const uint4*)&sTB[lm * S40 + qd * 8];
    TbF[1].u = *(const uint4*)&sTB[(16 + lm) * S40 + qd * 8];

    float kscj[8];
    #pragma unroll
    for (int j = 0; j < 8; j++) kscj[j] = skscL[qd * 8 + j];
    #pragma unroll
    for (int nt = 0; nt < 8; nt++) {
        U4H8 bV, bK;
        #pragma unroll
        for (int j = 0; j < 8; j++) {
            const long ro = tb + (long)(qd * 8 + j) * DK + nt * 16 + lm;
            bV.h[j] = (_Float16)vg[ro];
            bK.h[j] = (_Float16)(kg[ro] * kscj[j]);
        }
        ktf[((long)blk * 8 + nt) * 64 + l] = bK.u;
        f32x4 u0 = __builtin_amdgcn_mfma_f32_16x16x32_f16(TbF[0].h, bV.h, z4, 0, 0, 0);
        f32x4 u1 = __builtin_amdgcn_mfma_f32_16x16x32_f16(TbF[1].h, bV.h, z4, 0, 0, 0);
        uf[(((long)blk * 2 + 0) * 8 + nt) * 64 + l] = pk4(u0[0], u0[1], u0[2], u0[3]);
        uf[(((long)blk * 2 + 1) * 8 + nt) * 64 + l] = pk4(u1[0], u1[1], u1[2], u1[3]);
        f32x4 w0 = __builtin_amdgcn_mfma_f32_16x16x32_f16(TbF[0].h, bK.h, z4, 0, 0, 0);
        f32x4 w1 = __builtin_amdgcn_mfma_f32_16x16x32_f16(TbF[1].h, bK.h, z4, 0, 0, 0);
        #pragma unroll
        for (int r = 0; r < 4; r++) {
            sW[(qd * 4 + r) * S136 + nt * 16 + lm]        = (_Float16)(-w0[r]);
            sW[(16 + qd * 4 + r) * S136 + nt * 16 + lm]   = (_Float16)(-w1[r]);
        }
    }
    #pragma unroll
    for (int mt2 = 0; mt2 < 2; mt2++) {
        #pragma unroll
        for (int kt = 0; kt < 4; kt++) {
            uint4 x = *(const uint4*)&sW[(mt2 * 16 + lm) * S136 + kt * 32 + qd * 8];
            wnegf[((long)blk * 8 + mt2 * 4 + kt) * 64 + l] = x;
        }
    }
}

// ---------------- Phase 3a (exact round-3) ----------------
__global__ __launch_bounds__(64, 2) void phase3a_kernel(
    const uint4* __restrict__ wnegf, const uint4* __restrict__ ktf,
    const uint2* __restrict__ uf,
    uint4* __restrict__ Pf, uint2* __restrict__ Qgf)
{
    __shared__ alignas(16) _Float16 S16[16 * 16 * 8];
    __shared__ alignas(16) _Float16 U16[4 * 16 * 8];
    __shared__ alignas(16) _Float16 PT[128 * 16];

    const int l = threadIdx.x;
    const int lm = l & 15, quad = l >> 4;
    const int idx = blockIdx.x;
    const int s = idx >> 8;              // sharer 0..15
    const int g = idx & 255;             // bh*16+grp
    const int mode = s >> 3;             // 0 = Q-scan, 1 = P-scan
    const int w = s & 7;
    const int bh = g >> 4;
    const int grp = g & 15;
    const f32x4 z4 = {0.f, 0.f, 0.f, 0.f};

    if (mode && grp == 0) return;        // P_0 never used (S_0 = 0)

    f32x4 accS[8];
    #pragma unroll
    for (int mt = 0; mt < 8; mt++) {
        #pragma unroll
        for (int r = 0; r < 4; r++)
            accS[mt][r] = (mode && mt == w && quad * 4 + r == lm) ? 1.f : 0.f;
    }

    struct FragA { uint4 aW[2][4]; uint4 aK[8]; uint2 aU[2]; };
    FragA fA, fB;

    auto loadf = [&](FragA& f, int t) {
        const long blk = (long)bh * NCHUNK + grp * GSZ + t;
        #pragma unroll
        for (int mt2 = 0; mt2 < 2; mt2++)
            #pragma unroll
            for (int kt = 0; kt < 4; kt++)
                f.aW[mt2][kt] = wnegf[(blk * 8 + mt2 * 4 + kt) * 64 + l];
        #pragma unroll
        for (int mt = 0; mt < 8; mt++) f.aK[mt] = ktf[(blk * 8 + mt) * 64 + l];
        if (!mode) {
            #pragma unroll
            for (int mt2 = 0; mt2 < 2; mt2++)
                f.aU[mt2] = uf[((blk * 2 + mt2) * 8 + w) * 64 + l];
        }
    };

    auto compute = [&](const FragA& f) {
        #pragma unroll
        for (int mt = 0; mt < 8; mt++) {
            int g2 = 2 * mt + (quad >> 1);
            int sub = (quad & 1) * 4;
            *(uint2*)&S16[(g2 * 16 + lm) * 8 + sub] =
                pk4(accS[mt][0], accS[mt][1], accS[mt][2], accS[mt][3]);
        }
        f32x4 accU[2];
        #pragma unroll
        for (int mt2 = 0; mt2 < 2; mt2++)
            accU[mt2] = mode ? z4 : up4(f.aU[mt2]);
        #pragma unroll
        for (int kt = 0; kt < 4; kt++) {
            U4H8 bs;
            bs.u = *(const uint4*)&S16[((kt * 4 + quad) * 16 + lm) * 8];
            #pragma unroll
            for (int mt2 = 0; mt2 < 2; mt2++) {
                U4H8 aw; aw.u = f.aW[mt2][kt];
                accU[mt2] = __builtin_amdgcn_mfma_f32_16x16x32_f16(aw.h, bs.h, accU[mt2], 0, 0, 0);
            }
        }
        #pragma unroll
        for (int mt2 = 0; mt2 < 2; mt2++) {
            int g2 = 2 * mt2 + (quad >> 1);
            int sub = (quad & 1) * 4;
            *(uint2*)&U16[(g2 * 16 + lm) * 8 + sub] =
                pk4(accU[mt2][0], accU[mt2][1], accU[mt2][2], accU[mt2][3]);
        }
        U4H8 bu;
        bu.u = *(const uint4*)&U16[(quad * 16 + lm) * 8];
        #pragma unroll
        for (int mt = 0; mt < 8; mt++) {
            U4H8 ak; ak.u = f.aK[mt];
            accS[mt] = __builtin_amdgcn_mfma_f32_16x16x32_f16(ak.h, bu.h, accS[mt], 0, 0, 0);
        }
    };

    loadf(fA, 0);
    #pragma unroll 1
    for (int t = 0; t < GSZ; t += 2) {
        loadf(fB, t + 1);
        compute(fA);
        if (t + 2 < GSZ) loadf(fA, t + 2);
        compute(fB);
    }

    if (!mode) {
        const long qb = (((long)(bh * NG + grp)) * 8 + w) * 8 * 64;
        #pragma unroll
        for (int mt = 0; mt < 8; mt++)
            Qgf[qb + mt * 64 + l] = pk4(accS[mt][0], accS[mt][1], accS[mt][2], accS[mt][3]);
    } else {
        #pragma unroll
        for (int mt = 0; mt < 8; mt++)
            #pragma unroll
            for (int r = 0; r < 4; r++)
                PT[(mt * 16 + quad * 4 + r) * 16 + lm] = (_Float16)accS[mt][r];
        const int tl = ((w & 1) << 5) | (l & 31);
        const int half = l >> 5;
        const long pb = ((long)(bh * NG + grp)) * 8;
        #pragma unroll
        for (int i = 0; i < 4; i++) {
            int mt = half * 4 + i;
            uint4 x = *(const uint4*)&PT[(mt * 16 + (tl & 15)) * 16 + ((tl >> 4) & 1) * 8];
            Pf[((pb + mt) * 4 + (w >> 1)) * 64 + tl] = x;
        }
    }
}

// ---------------- Phase 3b: 4-wave serial group-state propagation (r9) ----------------
__global__ __launch_bounds__(256, 1) void phase3b_kernel(
    const uint4* __restrict__ Pf, const uint2* __restrict__ Qgf,
    uint2* __restrict__ Sjf, float* __restrict__ S_out)
{
    __shared__ alignas(16) _Float16 S16[2][16 * 16 * 8];

    const int tid = threadIdx.x;
    const int l = tid & 63;
    const int ww = tid >> 6;             // wave 0..3
    const int lm = l & 15, quad = l >> 4;
    const int bh = blockIdx.x & 15;
    const int w = blockIdx.x >> 4;

    f32x4 accS[2];
    #pragma unroll
    for (int i = 0; i < 2; i++) accS[i] = (f32x4){0.f, 0.f, 0.f, 0.f};

    uint2 Q0[2], Q1[2];
    uint4 P0[2][4], P1[2][4];

    auto loadQ = [&](uint2 (&Q)[2], int j) {
        const long b = (((long)(bh * NG + j)) * 8 + w) * 8 * 64;
        #pragma unroll
        for (int i = 0; i < 2; i++) Q[i] = Qgf[b + (ww * 2 + i) * 64 + l];
    };
    auto loadP = [&](uint4 (&P)[2][4], int j) {
        const long b = ((long)(bh * NG + j)) * 8;
        #pragma unroll
        for (int i = 0; i < 2; i++)
            #pragma unroll
            for (int kt = 0; kt < 4; kt++)
                P[i][kt] = Pf[((b + ww * 2 + i) * 4 + kt) * 64 + l];
    };
    auto computeB = [&](int j, const uint2 (&Q)[2], const uint4 (&P)[2][4]) {
        f32x4 ns[2];
        #pragma unroll
        for (int i = 0; i < 2; i++) ns[i] = up4(Q[i]);
        if (j) {
            const int buf = j & 1;
            #pragma unroll
            for (int i = 0; i < 2; i++) {
                int mt = ww * 2 + i;
                int g2 = 2 * mt + (quad >> 1);
                int sub = (quad & 1) * 4;
                *(uint2*)&S16[buf][(g2 * 16 + lm) * 8 + sub] =
                    pk4(accS[i][0], accS[i][1], accS[i][2], accS[i][3]);
            }
            __syncthreads();
            #pragma unroll
            for (int kt = 0; kt < 4; kt++) {
                U4H8 bs;
                bs.u = *(const uint4*)&S16[buf][((kt * 4 + quad) * 16 + lm) * 8];
                #pragma unroll
                for (int i = 0; i < 2; i++) {
                    U4H8 ap; ap.u = P[i][kt];
                    ns[i] = __builtin_amdgcn_mfma_f32_16x16x32_f16(ap.h, bs.h, ns[i], 0, 0, 0);
                }
            }
        }
        #pragma unroll
        for (int i = 0; i < 2; i++) accS[i] = ns[i];
        if (j < 15) {
            const long sb = (((long)(bh * 16 + (j + 1))) * 8 + w) * 8 * 64;
            #pragma unroll
            for (int i = 0; i < 2; i++)
                Sjf[sb + (ww * 2 + i) * 64 + l] = pk4(ns[i][0], ns[i][1], ns[i][2], ns[i][3]);
        } else {
            #pragma unroll
            for (int i = 0; i < 2; i++) {
                int mt = ww * 2 + i;
                #pragma unroll
                for (int r = 0; r < 4; r++)
                    S_out[(long)bh * (DK * DV) + (long)(mt * 16 + quad * 4 + r) * DV + w * 16 + lm] = ns[i][r];
            }
        }
    };

    loadQ(Q0, 0);
    loadP(P1, 1);
    #pragma unroll 1
    for (int j = 0; j < 16; j += 2) {
        loadQ(Q1, j + 1);
        computeB(j, Q0, P0);
        if (j + 2 < 16) { loadP(P0, j + 2); loadQ(Q0, j + 2); }
        computeB(j + 1, Q1, P1);
        if (j + 3 < 16) loadP(P1, j + 3);
    }
}

// ---------------- Phase 3c: 2-wave group replay, emit o ----------------
// 2048 blocks x 128 thr. Wave ww owns accS mt in {4ww..4ww+3}, accU/accO
// [mt2=ww], its frag slices; 2 barriers per chunk step (S16 publish, U16
// publish). Per-element MFMA order identical to the 1-wave version.
struct Frag2 {
    uint4 aW[4];
    uint4 aQ[4];
    uint4 aK[4];
    uint4 aAt;
    uint2 aU;
};

__global__ __launch_bounds__(128, 1) void phase3c_kernel(
    const uint4* __restrict__ wnegf, const uint4* __restrict__ qnf,
    const uint4* __restrict__ ktf, const uint4* __restrict__ atf,
    const uint2* __restrict__ uf, const uint2* __restrict__ Sjf,
    float* __restrict__ o_out)
{
    __shared__ alignas(16) _Float16 S16[16 * 16 * 8];  // 4KB
    __shared__ alignas(16) _Float16 U16[4 * 16 * 8];   // 1KB

    const int tid = threadIdx.x;
    const int l = tid & 63;
    const int ww = tid >> 6;             // wave 0/1
    const int lm = l & 15, quad = l >> 4;
    const int idx = blockIdx.x;
    const int w = idx >> 8;
    const int g = idx & 255;
    const int bh = g >> 4;
    const int grp = g & 15;
    const int dv = w * 16 + lm;

    f32x4 accS[4];
    if (grp == 0) {
        #pragma unroll
        for (int i = 0; i < 4; i++) accS[i] = (f32x4){0.f, 0.f, 0.f, 0.f};
    } else {
        const long sb = (((long)(bh * 16 + grp)) * 8 + w) * 8 * 64;
        #pragma unroll
        for (int i = 0; i < 4; i++) accS[i] = up4(Sjf[sb + (ww * 4 + i) * 64 + l]);
    }

    auto loadf = [&](Frag2& f, int t) {
        const long blk = (long)bh * NCHUNK + grp * GSZ + t;
        #pragma unroll
        for (int kt = 0; kt < 4; kt++) {
            f.aW[kt] = wnegf[(blk * 8 + ww * 4 + kt) * 64 + l];
            f.aQ[kt] = qnf[(blk * 8 + ww * 4 + kt) * 64 + l];
        }
        f.aAt = atf[(blk * 2 + ww) * 64 + l];
        f.aU = uf[((blk * 2 + ww) * 8 + w) * 64 + l];
        #pragma unroll
        for (int i = 0; i < 4; i++) f.aK[i] = ktf[(blk * 8 + ww * 4 + i) * 64 + l];
    };

    auto compute = [&](const Frag2& f, int t) {
        // Stage A: own 4 accS tiles -> S16; publish.
        #pragma unroll
        for (int i = 0; i < 4; i++) {
            int mt = ww * 4 + i;
            int g2 = 2 * mt + (quad >> 1);
            int sub = (quad & 1) * 4;
            *(uint2*)&S16[(g2 * 16 + lm) * 8 + sub] =
                pk4(accS[i][0], accS[i][1], accS[i][2], accS[i][3]);
        }
        __syncthreads();
        // Stage B: u_new[ww] = u + (-w)@S ; o_part[ww] = q@S (own mt2 = ww)
        f32x4 accU = up4(f.aU);
        f32x4 accO = (f32x4){0.f, 0.f, 0.f, 0.f};
        #pragma unroll
        for (int kt = 0; kt < 4; kt++) {
            U4H8 bs;
            bs.u = *(const uint4*)&S16[((kt * 4 + quad) * 16 + lm) * 8];
            U4H8 aw, aq;
            aw.u = f.aW[kt];
            aq.u = f.aQ[kt];
            accU = __builtin_amdgcn_mfma_f32_16x16x32_f16(aw.h, bs.h, accU, 0, 0, 0);
            accO = __builtin_amdgcn_mfma_f32_16x16x32_f16(aq.h, bs.h, accO, 0, 0, 0);
        }
        // Stage C: own u_new tile -> U16; publish.
        {
            int g2 = 2 * ww + (quad >> 1);
            int sub = (quad & 1) * 4;
            *(uint2*)&U16[(g2 * 16 + lm) * 8 + sub] =
                pk4(accU[0], accU[1], accU[2], accU[3]);
        }
        __syncthreads();
        // Stage D: o += attl @ u_new; store own rows (mt2 = ww)
        U4H8 bu;
        bu.u = *(const uint4*)&U16[(quad * 16 + lm) * 8];
        const long ob = ((long)bh * LSEQ + (long)(grp * GSZ + t) * C) * DV;
        U4H8 aa;
        aa.u = f.aAt;
        accO = __builtin_amdgcn_mfma_f32_16x16x32_f16(aa.h, bu.h, accO, 0, 0, 0);
        #pragma unroll
        for (int r = 0; r < 4; r++)
            o_out[ob + (long)(ww * 16 + quad * 4 + r) * DV + dv] = accO[r];
        // Stage E: S += kT @ u_new (own 4 mt)
        #pragma unroll
        for (int i = 0; i < 4; i++) {
            U4H8 ak;
            ak.u = f.aK[i];
            accS[i] = __builtin_amdgcn_mfma_f32_16x16x32_f16(ak.h, bu.h, accS[i], 0, 0, 0);
        }
    };

    Frag2 fA, fB;
    loadf(fA, 0);
    #pragma unroll 1
    for (int t = 0; t < GSZ; t += 2) {
        loadf(fB, t + 1);
        compute(fA, t);
        if (t + 2 < GSZ) loadf(fA, t + 2);
        compute(fB, t + 1);
    }
    // final S is written by phase3b.
}

extern "C" void kernel_launch(void* const* d_in, const int* in_sizes, int n_in,
                              void* d_out, int out_size, void* d_ws, size_t ws_size,
                              hipStream_t stream) {
    const float* q    = (const float*)d_in[0];
    const float* k    = (const float*)d_in[1];
    const float* v    = (const float*)d_in[2];
    const float* beta = (const float*)d_in[3];

    float* o = (float*)d_out;                      // [b,h,L,dv]
    float* S = o + (long)BH * LSEQ * DV;           // [b,h,dk,dv]

    const size_t nwq = (size_t)NBLK * 8 * 64;      // uint4 per A-frag file
    uint4* wnegf = (uint4*)d_ws;
    uint4* qnf = wnegf + nwq;
    uint4* ktf = qnf + nwq;
    uint4* atf = ktf + nwq;                        // NBLK*2*64 uint4
    uint2* uf  = (uint2*)(atf + (size_t)NBLK * 2 * 64);          // NBLK*16*64 uint2
    uint4* Pf  = (uint4*)(uf + (size_t)NBLK * 16 * 64);          // BH*NG*8*4*64 uint4
    uint2* Qgf = (uint2*)(Pf + (size_t)BH * NG * 8 * 4 * 64);    // BH*NG*8*8*64 uint2
    uint2* Sjf = Qgf + (size_t)BH * NG * 8 * 8 * 64;             // BH*16*8*8*64 uint2

    phase2_kernel<<<NBLK, 64, 0, stream>>>(q, k, v, beta, wnegf, qnf, ktf, atf, uf);
    phase3a_kernel<<<16 * 256, 64, 0, stream>>>(wnegf, ktf, uf, Pf, Qgf);
    phase3b_kernel<<<BH * 8, 256, 0, stream>>>(Pf, Qgf, Sjf, S);
    phase3c_kernel<<<8 * 256, 128, 0, stream>>>(wnegf, qnf, ktf, atf, uf, Sjf, o);
}

// Round 11
// 218.544 us; speedup vs baseline: 1.0710x; 1.0710x over previous
//
#include <hip/hip_runtime.h>
#include <hip/hip_bf16.h>

// DeltaNet chunkwise delta rule, b=2 h=8 L=4096 dk=dv=128 chunk=32.
// Phase2 (2048 wgs x 64 thr): round-3 stream with ONE change: the nt-loop's
//   v/k scalar loads are register-double-buffered one nt ahead (16 floats),
//   so each batch hides under a full iteration of MFMAs/stores instead of
//   serializing (r9 arithmetic: all blocks co-resident -> kernel dur = one
//   wave's wall time = 56us ~= 128 serial ~420ns loads; r4 spilled buffering
//   all 128, r5/r6 paid LDS roundtrips - this is the untried middle ground).
// Phase3 = two-level scan over S' = (I - k^T w) S + k^T u, 16 groups x 8
//   chunks, XCD-L2 sharing via block swizzle (round-3).
//   Phase3b (r9): 4-wave cooperative serial propagation (proven win).
//   Phase3c: r9 1-wave form (r10's 2-wave split regressed -14us: it traded
//   barrier-free TLP for sync overhead).

#define B 2
#define H 8
#define LSEQ 4096
#define DK 128
#define DV 128
#define C 32
#define NCHUNK (LSEQ / C)      // 128
#define BH (B * H)             // 16
#define NBLK (BH * NCHUNK)     // 2048
#define NG 16                  // groups
#define GSZ 8                  // chunks per group (NG*GSZ == NCHUNK)

typedef _Float16 f16x8 __attribute__((ext_vector_type(8)));
typedef float f32x4 __attribute__((ext_vector_type(4)));

union U4H8 { uint4 u; f16x8 h; };

__device__ inline unsigned short f2h(float f) {
    _Float16 h = (_Float16)f;
    unsigned short u;
    __builtin_memcpy(&u, &h, 2);
    return u;
}
__device__ inline float h2f(unsigned int v) {
    unsigned short s = (unsigned short)v;
    _Float16 h;
    __builtin_memcpy(&h, &s, 2);
    return (float)h;
}
__device__ inline unsigned int pack2(float a, float b) {
    return (unsigned int)f2h(a) | ((unsigned int)f2h(b) << 16);
}
__device__ inline float dot4(float4 a, float4 b) {
    return a.x * b.x + a.y * b.y + a.z * b.z + a.w * b.w;
}
__device__ inline float bf16r(float x) {
    return __bfloat162float(__float2bfloat16(x));
}
__device__ inline uint2 pk4(float v0, float v1, float v2, float v3) {
    uint2 p; p.x = pack2(v0, v1); p.y = pack2(v2, v3); return p;
}
__device__ inline f32x4 up4(uint2 p) {
    f32x4 v;
    v[0] = h2f(p.x & 0xffffu); v[1] = h2f(p.x >> 16);
    v[2] = h2f(p.y & 0xffffu); v[3] = h2f(p.y >> 16);
    return v;
}

// ---------------- Phase 2 ----------------
#define S40 40
#define S136 136

__global__ __launch_bounds__(64) void phase2_kernel(
    const float* __restrict__ qg, const float* __restrict__ kg,
    const float* __restrict__ vg, const float* __restrict__ betag,
    uint4* __restrict__ wnegf, uint4* __restrict__ qnf,
    uint4* __restrict__ ktf, uint4* __restrict__ atf,
    uint2* __restrict__ uf)
{
    __shared__ alignas(16) _Float16 sA [32 * S40];
    __shared__ alignas(16) _Float16 sAT[32 * S40];
    __shared__ alignas(16) _Float16 sTT[32 * S40];
    __shared__ alignas(16) _Float16 sTB[32 * S40];
    __shared__ alignas(16) _Float16 sW [32 * S136];
    __shared__ alignas(16) float sbetaL[32];
    __shared__ alignas(16) float skscL[32];

    const int l = threadIdx.x;
    const int lm = l & 15, qd = l >> 4;
    const int blk = blockIdx.x;
    const long tb = (long)blk * C * DK;
    const f32x4 z4 = {0.f, 0.f, 0.f, 0.f};

    if (l < 32) sbetaL[l] = betag[(long)blk * C + l];

    U4H8 qF[8], kF[8];
    float ssq[2] = {0.f, 0.f}, ssk[2] = {0.f, 0.f};
    #pragma unroll
    for (int mt = 0; mt < 2; mt++) {
        #pragma unroll
        for (int kt = 0; kt < 4; kt++) {
            const float* qp = qg + tb + (long)(mt * 16 + lm) * DK + kt * 32 + qd * 8;
            const float* kp = kg + tb + (long)(mt * 16 + lm) * DK + kt * 32 + qd * 8;
            float4 a0 = *(const float4*)qp, a1 = *(const float4*)(qp + 4);
            float4 b0 = *(const float4*)kp, b1 = *(const float4*)(kp + 4);
            ssq[mt] += dot4(a0, a0) + dot4(a1, a1);
            ssk[mt] += dot4(b0, b0) + dot4(b1, b1);
            U4H8 x;
            x.u.x = pack2(a0.x, a0.y); x.u.y = pack2(a0.z, a0.w);
            x.u.z = pack2(a1.x, a1.y); x.u.w = pack2(a1.z, a1.w);
            qF[mt * 4 + kt] = x;
            U4H8 y;
            y.u.x = pack2(b0.x, b0.y); y.u.y = pack2(b0.z, b0.w);
            y.u.z = pack2(b1.x, b1.y); y.u.w = pack2(b1.z, b1.w);
            kF[mt * 4 + kt] = y;
        }
    }
    float qsc[2], ksc[2];
    #pragma unroll
    for (int mt = 0; mt < 2; mt++) {
        float s = ssq[mt];
        s += __shfl_xor(s, 16, 64);
        s += __shfl_xor(s, 32, 64);
        qsc[mt] = rsqrtf(s + 1e-6f);
        float t = ssk[mt];
        t += __shfl_xor(t, 16, 64);
        t += __shfl_xor(t, 32, 64);
        ksc[mt] = rsqrtf(t + 1e-6f);
    }
    if (qd == 0) { skscL[lm] = ksc[0]; skscL[16 + lm] = ksc[1]; }

    f32x4 alT[3] = {z4, z4, z4};
    #pragma unroll
    for (int kt = 0; kt < 4; kt++) {
        alT[0] = __builtin_amdgcn_mfma_f32_16x16x32_f16(kF[kt].h,     qF[kt].h,     alT[0], 0, 0, 0);
        alT[1] = __builtin_amdgcn_mfma_f32_16x16x32_f16(kF[kt].h,     qF[4 + kt].h, alT[1], 0, 0, 0);
        alT[2] = __builtin_amdgcn_mfma_f32_16x16x32_f16(kF[4 + kt].h, qF[4 + kt].h, alT[2], 0, 0, 0);
    }
    #pragma unroll
    for (int mt = 0; mt < 2; mt++) {
        _Float16 qs = (_Float16)qsc[mt];
        #pragma unroll
        for (int kt = 0; kt < 4; kt++) {
            U4H8 x;
            x.h = qF[mt * 4 + kt].h * qs;
            qnf[((long)blk * 8 + mt * 4 + kt) * 64 + l] = x.u;
        }
    }
    f32x4 rw[4] = {z4, z4, z4, z4};
    #pragma unroll
    for (int kt = 0; kt < 4; kt++) {
        rw[0] = __builtin_amdgcn_mfma_f32_16x16x32_f16(kF[kt].h,     kF[kt].h,     rw[0], 0, 0, 0);
        rw[1] = __builtin_amdgcn_mfma_f32_16x16x32_f16(kF[kt].h,     kF[4 + kt].h, rw[1], 0, 0, 0);
        rw[2] = __builtin_amdgcn_mfma_f32_16x16x32_f16(kF[4 + kt].h, kF[kt].h,     rw[2], 0, 0, 0);
        rw[3] = __builtin_amdgcn_mfma_f32_16x16x32_f16(kF[4 + kt].h, kF[4 + kt].h, rw[3], 0, 0, 0);
    }

    float4 b4[2], ks4[2];
    b4[0]  = *(const float4*)&sbetaL[qd * 4];      b4[1]  = *(const float4*)&sbetaL[16 + qd * 4];
    ks4[0] = *(const float4*)&skscL[qd * 4];       ks4[1] = *(const float4*)&skscL[16 + qd * 4];
    const float bcol0 = sbetaL[lm], bcol1 = sbetaL[16 + lm];

    {
        *(uint2*)&sTB[lm * S40 + 16 + qd * 4] = (uint2){0u, 0u};
        float v[4];
        #pragma unroll
        for (int r = 0; r < 4; r++) {
            int c = qd * 4 + r;
            v[r] = (c <= lm) ? (qsc[0] * (&ks4[0].x)[r] * alT[0][r]) : 0.f;
        }
        *(uint2*)&sTB[lm * S40 + qd * 4] = pk4(v[0], v[1], v[2], v[3]);
        #pragma unroll
        for (int r = 0; r < 4; r++) v[r] = qsc[1] * (&ks4[0].x)[r] * alT[1][r];
        *(uint2*)&sTB[(16 + lm) * S40 + qd * 4] = pk4(v[0], v[1], v[2], v[3]);
        #pragma unroll
        for (int r = 0; r < 4; r++) {
            int c = qd * 4 + r;
            v[r] = (c <= lm) ? (qsc[1] * (&ks4[1].x)[r] * alT[2][r]) : 0.f;
        }
        *(uint2*)&sTB[(16 + lm) * S40 + 16 + qd * 4] = pk4(v[0], v[1], v[2], v[3]);
    }
    #pragma unroll
    for (int f = 0; f < 2; f++) {
        uint4 x = *(const uint4*)&sTB[(f * 16 + lm) * S40 + qd * 8];
        atf[((long)blk * 2 + f) * 64 + l] = x;
    }

    {
        float v[4];
        *(uint2*)&sA [lm * S40 + 16 + qd * 4]        = (uint2){0u, 0u};
        *(uint2*)&sAT[(16 + lm) * S40 + qd * 4]      = (uint2){0u, 0u};
        *(uint2*)&sTT[(16 + lm) * S40 + qd * 4]      = (uint2){0u, 0u};
        #pragma unroll
        for (int r = 0; r < 4; r++) {
            int c = qd * 4 + r;
            v[r] = (c < lm) ? (-bcol0 * ksc[0] * (&ks4[0].x)[r] * rw[0][r]) : 0.f;
        }
        *(uint2*)&sA[lm * S40 + qd * 4] = pk4(v[0], v[1], v[2], v[3]);
        #pragma unroll
        for (int r = 0; r < 4; r++) v[r] = -bcol1 * ksc[1] * (&ks4[0].x)[r] * rw[1][r];
        *(uint2*)&sA[(16 + lm) * S40 + qd * 4] = pk4(v[0], v[1], v[2], v[3]);
        #pragma unroll
        for (int r = 0; r < 4; r++) {
            int c = qd * 4 + r;
            v[r] = (c < lm) ? (-bcol1 * ksc[1] * (&ks4[1].x)[r] * rw[3][r]) : 0.f;
        }
        *(uint2*)&sA[(16 + lm) * S40 + 16 + qd * 4] = pk4(v[0], v[1], v[2], v[3]);
        #pragma unroll
        for (int r = 0; r < 4; r++) {
            int c = qd * 4 + r;
            v[r] = (c > lm) ? (-(&b4[0].x)[r] * (&ks4[0].x)[r] * ksc[0] * rw[0][r]) : 0.f;
        }
        *(uint2*)&sAT[lm * S40 + qd * 4] = pk4(v[0], v[1], v[2], v[3]);
        #pragma unroll
        for (int r = 0; r < 4; r++) v[r] = -(&b4[1].x)[r] * (&ks4[1].x)[r] * ksc[0] * rw[2][r];
        *(uint2*)&sAT[lm * S40 + 16 + qd * 4] = pk4(v[0], v[1], v[2], v[3]);
        #pragma unroll
        for (int r = 0; r < 4; r++) {
            int c = qd * 4 + r;
            v[r] = (c > lm) ? (-(&b4[1].x)[r] * (&ks4[1].x)[r] * ksc[1] * rw[3][r]) : 0.f;
        }
        *(uint2*)&sAT[(16 + lm) * S40 + 16 + qd * 4] = pk4(v[0], v[1], v[2], v[3]);
        #pragma unroll
        for (int r = 0; r < 4; r++) {
            int c = qd * 4 + r;
            v[r] = (c > lm) ? (-(&b4[0].x)[r] * (&ks4[0].x)[r] * ksc[0] * rw[0][r])
                            : ((c == lm) ? 1.0f : 0.f);
        }
        *(uint2*)&sTT[lm * S40 + qd * 4] = pk4(v[0], v[1], v[2], v[3]);
        #pragma unroll
        for (int r = 0; r < 4; r++) v[r] = -(&b4[1].x)[r] * (&ks4[1].x)[r] * ksc[0] * rw[2][r];
        *(uint2*)&sTT[lm * S40 + 16 + qd * 4] = pk4(v[0], v[1], v[2], v[3]);
        #pragma unroll
        for (int r = 0; r < 4; r++) {
            int c = qd * 4 + r;
            v[r] = (c > lm) ? (-(&b4[1].x)[r] * (&ks4[1].x)[r] * ksc[1] * rw[3][r])
                            : ((c == lm) ? 1.0f : 0.f);
        }
        *(uint2*)&sTT[(16 + lm) * S40 + 16 + qd * 4] = pk4(v[0], v[1], v[2], v[3]);
    }
    f32x4 Tc[3], TTc[3];
    #pragma unroll
    for (int r = 0; r < 4; r++) {
        int rr = qd * 4 + r;
        Tc[0][r] = (lm < rr) ? (-(&b4[0].x)[r] * (&ks4[0].x)[r] * ksc[0] * rw[0][r])
                             : ((lm == rr) ? 1.0f : 0.f);
        Tc[1][r] = -(&b4[1].x)[r] * (&ks4[1].x)[r] * ksc[0] * rw[2][r];
        Tc[2][r] = (lm < rr) ? (-(&b4[1].x)[r] * (&ks4[1].x)[r] * ksc[1] * rw[3][r])
                             : ((lm == rr) ? 1.0f : 0.f);
        TTc[0][r] = (rr < lm) ? (-bcol0 * ksc[0] * (&ks4[0].x)[r] * rw[0][r])
                              : ((rr == lm) ? 1.0f : 0.f);
        TTc[1][r] = -bcol1 * ksc[1] * (&ks4[0].x)[r] * rw[1][r];
        TTc[2][r] = (rr < lm) ? (-bcol1 * ksc[1] * (&ks4[1].x)[r] * rw[3][r])
                              : ((rr == lm) ? 1.0f : 0.f);
    }

    #pragma unroll
    for (int p = 0; p < 4; p++) {
        U4H8 AF[2], ATF[2], TTF[2];
        AF[0].u  = *(const uint4*)&sA [lm * S40 + qd * 8];
        AF[1].u  = *(const uint4*)&sA [(16 + lm) * S40 + qd * 8];
        ATF[0].u = *(const uint4*)&sAT[lm * S40 + qd * 8];
        ATF[1].u = *(const uint4*)&sAT[(16 + lm) * S40 + qd * 8];
        TTF[0].u = *(const uint4*)&sTT[lm * S40 + qd * 8];
        TTF[1].u = *(const uint4*)&sTT[(16 + lm) * S40 + qd * 8];

        f32x4 A2_00 = __builtin_amdgcn_mfma_f32_16x16x32_f16(AF[0].h, ATF[0].h, z4, 0, 0, 0);
        f32x4 A2_10 = __builtin_amdgcn_mfma_f32_16x16x32_f16(AF[1].h, ATF[0].h, z4, 0, 0, 0);
        f32x4 A2_11 = __builtin_amdgcn_mfma_f32_16x16x32_f16(AF[1].h, ATF[1].h, z4, 0, 0, 0);
        f32x4 A2T_00 = __builtin_amdgcn_mfma_f32_16x16x32_f16(ATF[0].h, AF[0].h, z4, 0, 0, 0);
        f32x4 A2T_01 = __builtin_amdgcn_mfma_f32_16x16x32_f16(ATF[0].h, AF[1].h, z4, 0, 0, 0);
        f32x4 A2T_11 = __builtin_amdgcn_mfma_f32_16x16x32_f16(ATF[1].h, AF[1].h, z4, 0, 0, 0);

        {
            float v[4];
            #pragma unroll
            for (int r = 0; r < 4; r++) { int c = qd * 4 + r; v[r] = (c < lm) ? A2T_00[r] : 0.f; }
            *(uint2*)&sA[lm * S40 + qd * 4] = pk4(v[0], v[1], v[2], v[3]);
            *(uint2*)&sA[(16 + lm) * S40 + qd * 4] = pk4(A2T_01[0], A2T_01[1], A2T_01[2], A2T_01[3]);
            #pragma unroll
            for (int r = 0; r < 4; r++) { int c = qd * 4 + r; v[r] = (c < lm) ? A2T_11[r] : 0.f; }
            *(uint2*)&sA[(16 + lm) * S40 + 16 + qd * 4] = pk4(v[0], v[1], v[2], v[3]);
        }
        if (p < 3) {
            float v[4];
            #pragma unroll
            for (int r = 0; r < 4; r++) { int c = qd * 4 + r; v[r] = (c > lm) ? A2_00[r] : 0.f; }
            *(uint2*)&sAT[lm * S40 + qd * 4] = pk4(v[0], v[1], v[2], v[3]);
            *(uint2*)&sAT[lm * S40 + 16 + qd * 4] = pk4(A2_10[0], A2_10[1], A2_10[2], A2_10[3]);
            #pragma unroll
            for (int r = 0; r < 4; r++) { int c = qd * 4 + r; v[r] = (c > lm) ? A2_11[r] : 0.f; }
            *(uint2*)&sAT[(16 + lm) * S40 + 16 + qd * 4] = pk4(v[0], v[1], v[2], v[3]);
        }
        U4H8 AnF[2];
        AnF[0].u = *(const uint4*)&sA[lm * S40 + qd * 8];
        AnF[1].u = *(const uint4*)&sA[(16 + lm) * S40 + qd * 8];
        Tc[0]  = __builtin_amdgcn_mfma_f32_16x16x32_f16(AnF[0].h, TTF[0].h, Tc[0], 0, 0, 0);
        Tc[1]  = __builtin_amdgcn_mfma_f32_16x16x32_f16(AnF[1].h, TTF[0].h, Tc[1], 0, 0, 0);
        Tc[2]  = __builtin_amdgcn_mfma_f32_16x16x32_f16(AnF[1].h, TTF[1].h, Tc[2], 0, 0, 0);
        TTc[0] = __builtin_amdgcn_mfma_f32_16x16x32_f16(TTF[0].h, AnF[0].h, TTc[0], 0, 0, 0);
        TTc[1] = __builtin_amdgcn_mfma_f32_16x16x32_f16(TTF[0].h, AnF[1].h, TTc[1], 0, 0, 0);
        TTc[2] = __builtin_amdgcn_mfma_f32_16x16x32_f16(TTF[1].h, AnF[1].h, TTc[2], 0, 0, 0);
        if (p < 3) {
            *(uint2*)&sTT[lm * S40 + qd * 4]             = pk4(Tc[0][0], Tc[0][1], Tc[0][2], Tc[0][3]);
            *(uint2*)&sTT[lm * S40 + 16 + qd * 4]        = pk4(Tc[1][0], Tc[1][1], Tc[1][2], Tc[1][3]);
            *(uint2*)&sTT[(16 + lm) * S40 + 16 + qd * 4] = pk4(Tc[2][0], Tc[2][1], Tc[2][2], Tc[2][3]);
        }
    }

    {
        *(uint2*)&sTB[lm * S40 + 16 + qd * 4] = (uint2){0u, 0u};
        float v[4];
        #pragma unroll
        for (int r = 0; r < 4; r++) v[r] = bf16r(TTc[0][r]) * (&b4[0].x)[r];
        *(uint2*)&sTB[lm * S40 + qd * 4] = pk4(v[0], v[1], v[2], v[3]);
        #pragma unroll
        for (int r = 0; r < 4; r++) v[r] = bf16r(TTc[1][r]) * (&b4[0].x)[r];
        *(uint2*)&sTB[(16 + lm) * S40 + qd * 4] = pk4(v[0], v[1], v[2], v[3]);
        #pragma unroll
        for (int r = 0; r < 4; r++) v[r] = bf16r(TTc[2][r]) * (&b4[1].x)[r];
        *(uint2*)&sTB[(16 + lm) * S40 + 16 + qd * 4] = pk4(v[0], v[1], v[2], v[3]);
    }
    U4H8 TbF[2];
    TbF[0].u = *(const uint4*)&sTB[lm * S40 + qd * 8];
    TbF[1].u = *(const uint4*)&sTB[(16 + lm) * S40 + qd * 8];

    // ---- u, w, ktf, wneg: register-double-buffered v/k tile loads ----
    float kscj[8];
    #pragma unroll
    for (int j = 0; j < 8; j++) kscj[j] = skscL[qd * 8 + j];
    float vbuf[2][8], kbuf[2][8];
    #pragma unroll
    for (int j = 0; j < 8; j++) {
        const long ro = tb + (long)(qd * 8 + j) * DK + lm;
        vbuf[0][j] = vg[ro];
        kbuf[0][j] = kg[ro];
    }
    #pragma unroll
    for (int nt = 0; nt < 8; nt++) {
        const int cur = nt & 1, nxt = cur ^ 1;
        if (nt < 7) {
            #pragma unroll
            for (int j = 0; j < 8; j++) {
                const long ro = tb + (long)(qd * 8 + j) * DK + (nt + 1) * 16 + lm;
                vbuf[nxt][j] = vg[ro];
                kbuf[nxt][j] = kg[ro];
            }
        }
        U4H8 bV, bK;
        #pragma unroll
        for (int j = 0; j < 8; j++) {
            bV.h[j] = (_Float16)vbuf[cur][j];
            bK.h[j] = (_Float16)(kbuf[cur][j] * kscj[j]);
        }
        ktf[((long)blk * 8 + nt) * 64 + l] = bK.u;
        f32x4 u0 = __builtin_amdgcn_mfma_f32_16x16x32_f16(TbF[0].h, bV.h, z4, 0, 0, 0);
        f32x4 u1 = __builtin_amdgcn_mfma_f32_16x16x32_f16(TbF[1].h, bV.h, z4, 0, 0, 0);
        uf[(((long)blk * 2 + 0) * 8 + nt) * 64 + l] = pk4(u0[0], u0[1], u0[2], u0[3]);
        uf[(((long)blk * 2 + 1) * 8 + nt) * 64 + l] = pk4(u1[0], u1[1], u1[2], u1[3]);
        f32x4 w0 = __builtin_amdgcn_mfma_f32_16x16x32_f16(TbF[0].h, bK.h, z4, 0, 0, 0);
        f32x4 w1 = __builtin_amdgcn_mfma_f32_16x16x32_f16(TbF[1].h, bK.h, z4, 0, 0, 0);
        #pragma unroll
        for (int r = 0; r < 4; r++) {
            sW[(qd * 4 + r) * S136 + nt * 16 + lm]        = (_Float16)(-w0[r]);
            sW[(16 + qd * 4 + r) * S136 + nt * 16 + lm]   = (_Float16)(-w1[r]);
        }
    }
    #pragma unroll
    for (int mt2 = 0; mt2 < 2; mt2++) {
        #pragma unroll
        for (int kt = 0; kt < 4; kt++) {
            uint4 x = *(const uint4*)&sW[(mt2 * 16 + lm) * S136 + kt * 32 + qd * 8];
            wnegf[((long)blk * 8 + mt2 * 4 + kt) * 64 + l] = x;
        }
    }
}

// ---------------- Phase 3a (exact round-3) ----------------
__global__ __launch_bounds__(64, 2) void phase3a_kernel(
    const uint4* __restrict__ wnegf, const uint4* __restrict__ ktf,
    const uint2* __restrict__ uf,
    uint4* __restrict__ Pf, uint2* __restrict__ Qgf)
{
    __shared__ alignas(16) _Float16 S16[16 * 16 * 8];
    __shared__ alignas(16) _Float16 U16[4 * 16 * 8];
    __shared__ alignas(16) _Float16 PT[128 * 16];

    const int l = threadIdx.x;
    const int lm = l & 15, quad = l >> 4;
    const int idx = blockIdx.x;
    const int s = idx >> 8;              // sharer 0..15
    const int g = idx & 255;             // bh*16+grp
    const int mode = s >> 3;             // 0 = Q-scan, 1 = P-scan
    const int w = s & 7;
    const int bh = g >> 4;
    const int grp = g & 15;
    const f32x4 z4 = {0.f, 0.f, 0.f, 0.f};

    if (mode && grp == 0) return;        // P_0 never used (S_0 = 0)

    f32x4 accS[8];
    #pragma unroll
    for (int mt = 0; mt < 8; mt++) {
        #pragma unroll
        for (int r = 0; r < 4; r++)
            accS[mt][r] = (mode && mt == w && quad * 4 + r == lm) ? 1.f : 0.f;
    }

    struct FragA { uint4 aW[2][4]; uint4 aK[8]; uint2 aU[2]; };
    FragA fA, fB;

    auto loadf = [&](FragA& f, int t) {
        const long blk = (long)bh * NCHUNK + grp * GSZ + t;
        #pragma unroll
        for (int mt2 = 0; mt2 < 2; mt2++)
            #pragma unroll
            for (int kt = 0; kt < 4; kt++)
                f.aW[mt2][kt] = wnegf[(blk * 8 + mt2 * 4 + kt) * 64 + l];
        #pragma unroll
        for (int mt = 0; mt < 8; mt++) f.aK[mt] = ktf[(blk * 8 + mt) * 64 + l];
        if (!mode) {
            #pragma unroll
            for (int mt2 = 0; mt2 < 2; mt2++)
                f.aU[mt2] = uf[((blk * 2 + mt2) * 8 + w) * 64 + l];
        }
    };

    auto compute = [&](const FragA& f) {
        #pragma unroll
        for (int mt = 0; mt < 8; mt++) {
            int g2 = 2 * mt + (quad >> 1);
            int sub = (quad & 1) * 4;
            *(uint2*)&S16[(g2 * 16 + lm) * 8 + sub] =
                pk4(accS[mt][0], accS[mt][1], accS[mt][2], accS[mt][3]);
        }
        f32x4 accU[2];
        #pragma unroll
        for (int mt2 = 0; mt2 < 2; mt2++)
            accU[mt2] = mode ? z4 : up4(f.aU[mt2]);
        #pragma unroll
        for (int kt = 0; kt < 4; kt++) {
            U4H8 bs;
            bs.u = *(const uint4*)&S16[((kt * 4 + quad) * 16 + lm) * 8];
            #pragma unroll
            for (int mt2 = 0; mt2 < 2; mt2++) {
                U4H8 aw; aw.u = f.aW[mt2][kt];
                accU[mt2] = __builtin_amdgcn_mfma_f32_16x16x32_f16(aw.h, bs.h, accU[mt2], 0, 0, 0);
            }
        }
        #pragma unroll
        for (int mt2 = 0; mt2 < 2; mt2++) {
            int g2 = 2 * mt2 + (quad >> 1);
            int sub = (quad & 1) * 4;
            *(uint2*)&U16[(g2 * 16 + lm) * 8 + sub] =
                pk4(accU[mt2][0], accU[mt2][1], accU[mt2][2], accU[mt2][3]);
        }
        U4H8 bu;
        bu.u = *(const uint4*)&U16[(quad * 16 + lm) * 8];
        #pragma unroll
        for (int mt = 0; mt < 8; mt++) {
            U4H8 ak; ak.u = f.aK[mt];
            accS[mt] = __builtin_amdgcn_mfma_f32_16x16x32_f16(ak.h, bu.h, accS[mt], 0, 0, 0);
        }
    };

    loadf(fA, 0);
    #pragma unroll 1
    for (int t = 0; t < GSZ; t += 2) {
        loadf(fB, t + 1);
        compute(fA);
        if (t + 2 < GSZ) loadf(fA, t + 2);
        compute(fB);
    }

    if (!mode) {
        const long qb = (((long)(bh * NG + grp)) * 8 + w) * 8 * 64;
        #pragma unroll
        for (int mt = 0; mt < 8; mt++)
            Qgf[qb + mt * 64 + l] = pk4(accS[mt][0], accS[mt][1], accS[mt][2], accS[mt][3]);
    } else {
        #pragma unroll
        for (int mt = 0; mt < 8; mt++)
            #pragma unroll
            for (int r = 0; r < 4; r++)
                PT[(mt * 16 + quad * 4 + r) * 16 + lm] = (_Float16)accS[mt][r];
        const int tl = ((w & 1) << 5) | (l & 31);
        const int half = l >> 5;
        const long pb = ((long)(bh * NG + grp)) * 8;
        #pragma unroll
        for (int i = 0; i < 4; i++) {
            int mt = half * 4 + i;
            uint4 x = *(const uint4*)&PT[(mt * 16 + (tl & 15)) * 16 + ((tl >> 4) & 1) * 8];
            Pf[((pb + mt) * 4 + (w >> 1)) * 64 + tl] = x;
        }
    }
}

// ---------------- Phase 3b: 4-wave serial group-state propagation (r9) ----------------
__global__ __launch_bounds__(256, 1) void phase3b_kernel(
    const uint4* __restrict__ Pf, const uint2* __restrict__ Qgf,
    uint2* __restrict__ Sjf, float* __restrict__ S_out)
{
    __shared__ alignas(16) _Float16 S16[2][16 * 16 * 8];

    const int tid = threadIdx.x;
    const int l = tid & 63;
    const int ww = tid >> 6;             // wave 0..3
    const int lm = l & 15, quad = l >> 4;
    const int bh = blockIdx.x & 15;
    const int w = blockIdx.x >> 4;

    f32x4 accS[2];
    #pragma unroll
    for (int i = 0; i < 2; i++) accS[i] = (f32x4){0.f, 0.f, 0.f, 0.f};

    uint2 Q0[2], Q1[2];
    uint4 P0[2][4], P1[2][4];

    auto loadQ = [&](uint2 (&Q)[2], int j) {
        const long b = (((long)(bh * NG + j)) * 8 + w) * 8 * 64;
        #pragma unroll
        for (int i = 0; i < 2; i++) Q[i] = Qgf[b + (ww * 2 + i) * 64 + l];
    };
    auto loadP = [&](uint4 (&P)[2][4], int j) {
        const long b = ((long)(bh * NG + j)) * 8;
        #pragma unroll
        for (int i = 0; i < 2; i++)
            #pragma unroll
            for (int kt = 0; kt < 4; kt++)
                P[i][kt] = Pf[((b + ww * 2 + i) * 4 + kt) * 64 + l];
    };
    auto computeB = [&](int j, const uint2 (&Q)[2], const uint4 (&P)[2][4]) {
        f32x4 ns[2];
        #pragma unroll
        for (int i = 0; i < 2; i++) ns[i] = up4(Q[i]);
        if (j) {
            const int buf = j & 1;
            #pragma unroll
            for (int i = 0; i < 2; i++) {
                int mt = ww * 2 + i;
                int g2 = 2 * mt + (quad >> 1);
                int sub = (quad & 1) * 4;
                *(uint2*)&S16[buf][(g2 * 16 + lm) * 8 + sub] =
                    pk4(accS[i][0], accS[i][1], accS[i][2], accS[i][3]);
            }
            __syncthreads();
            #pragma unroll
            for (int kt = 0; kt < 4; kt++) {
                U4H8 bs;
                bs.u = *(const uint4*)&S16[buf][((kt * 4 + quad) * 16 + lm) * 8];
                #pragma unroll
                for (int i = 0; i < 2; i++) {
                    U4H8 ap; ap.u = P[i][kt];
                    ns[i] = __builtin_amdgcn_mfma_f32_16x16x32_f16(ap.h, bs.h, ns[i], 0, 0, 0);
                }
            }
        }
        #pragma unroll
        for (int i = 0; i < 2; i++) accS[i] = ns[i];
        if (j < 15) {
            const long sb = (((long)(bh * 16 + (j + 1))) * 8 + w) * 8 * 64;
            #pragma unroll
            for (int i = 0; i < 2; i++)
                Sjf[sb + (ww * 2 + i) * 64 + l] = pk4(ns[i][0], ns[i][1], ns[i][2], ns[i][3]);
        } else {
            #pragma unroll
            for (int i = 0; i < 2; i++) {
                int mt = ww * 2 + i;
                #pragma unroll
                for (int r = 0; r < 4; r++)
                    S_out[(long)bh * (DK * DV) + (long)(mt * 16 + quad * 4 + r) * DV + w * 16 + lm] = ns[i][r];
            }
        }
    };

    loadQ(Q0, 0);
    loadP(P1, 1);
    #pragma unroll 1
    for (int j = 0; j < 16; j += 2) {
        loadQ(Q1, j + 1);
        computeB(j, Q0, P0);
        if (j + 2 < 16) { loadP(P0, j + 2); loadQ(Q0, j + 2); }
        computeB(j + 1, Q1, P1);
        if (j + 3 < 16) loadP(P1, j + 3);
    }
}

// ---------------- Phase 3c: 1-wave group replay (r9), emit o ----------------
struct Frags {
    uint4 aW[2][4];
    uint4 aQ[2][4];
    uint4 aK[8];
    uint4 aAt[2];
    uint2 aU[2];
};

__global__ __launch_bounds__(64, 1) void phase3c_kernel(
    const uint4* __restrict__ wnegf, const uint4* __restrict__ qnf,
    const uint4* __restrict__ ktf, const uint4* __restrict__ atf,
    const uint2* __restrict__ uf, const uint2* __restrict__ Sjf,
    float* __restrict__ o_out)
{
    __shared__ alignas(16) _Float16 S16[16 * 16 * 8];  // 4KB
    __shared__ alignas(16) _Float16 U16[4 * 16 * 8];   // 1KB

    const int l = threadIdx.x;
    const int lm = l & 15, quad = l >> 4;
    const int idx = blockIdx.x;
    const int w = idx >> 8;
    const int g = idx & 255;
    const int bh = g >> 4;
    const int grp = g & 15;
    const int dv = w * 16 + lm;

    f32x4 accS[8];
    if (grp == 0) {
        #pragma unroll
        for (int mt = 0; mt < 8; mt++) accS[mt] = (f32x4){0.f, 0.f, 0.f, 0.f};
    } else {
        const long sb = (((long)(bh * 16 + grp)) * 8 + w) * 8 * 64;
        #pragma unroll
        for (int mt = 0; mt < 8; mt++) accS[mt] = up4(Sjf[sb + mt * 64 + l]);
    }

    auto loadf = [&](Frags& f, int t) {
        const long blk = (long)bh * NCHUNK + grp * GSZ + t;
        #pragma unroll
        for (int mt2 = 0; mt2 < 2; mt2++) {
            #pragma unroll
            for (int kt = 0; kt < 4; kt++) {
                f.aW[mt2][kt] = wnegf[(blk * 8 + mt2 * 4 + kt) * 64 + l];
                f.aQ[mt2][kt] = qnf[(blk * 8 + mt2 * 4 + kt) * 64 + l];
            }
            f.aAt[mt2] = atf[(blk * 2 + mt2) * 64 + l];
            f.aU[mt2] = uf[((blk * 2 + mt2) * 8 + w) * 64 + l];
        }
        #pragma unroll
        for (int mt = 0; mt < 8; mt++) f.aK[mt] = ktf[(blk * 8 + mt) * 64 + l];
    };

    auto compute = [&](const Frags& f, int t) {
        #pragma unroll
        for (int mt = 0; mt < 8; mt++) {
            int g2 = 2 * mt + (quad >> 1);
            int sub = (quad & 1) * 4;
            *(uint2*)&S16[(g2 * 16 + lm) * 8 + sub] =
                pk4(accS[mt][0], accS[mt][1], accS[mt][2], accS[mt][3]);
        }
        f32x4 accU[2], accO[2];
        #pragma unroll
        for (int mt2 = 0; mt2 < 2; mt2++) {
            accU[mt2] = up4(f.aU[mt2]);
            accO[mt2] = (f32x4){0.f, 0.f, 0.f, 0.f};
        }
        #pragma unroll
        for (int kt = 0; kt < 4; kt++) {
            U4H8 bs;
            bs.u = *(const uint4*)&S16[((kt * 4 + quad) * 16 + lm) * 8];
            #pragma unroll
            for (int mt2 = 0; mt2 < 2; mt2++) {
                U4H8 aw, aq;
                aw.u = f.aW[mt2][kt];
                aq.u = f.aQ[mt2][kt];
                accU[mt2] = __builtin_amdgcn_mfma_f32_16x16x32_f16(aw.h, bs.h, accU[mt2], 0, 0, 0);
                accO[mt2] = __builtin_amdgcn_mfma_f32_16x16x32_f16(aq.h, bs.h, accO[mt2], 0, 0, 0);
            }
        }
        #pragma unroll
        for (int mt2 = 0; mt2 < 2; mt2++) {
            int g2 = 2 * mt2 + (quad >> 1);
            int sub = (quad & 1) * 4;
            *(uint2*)&U16[(g2 * 16 + lm) * 8 + sub] =
                pk4(accU[mt2][0], accU[mt2][1], accU[mt2][2], accU[mt2][3]);
        }
        U4H8 bu;
        bu.u = *(const uint4*)&U16[(quad * 16 + lm) * 8];
        const long ob = ((long)bh * LSEQ + (long)(grp * GSZ + t) * C) * DV;
        #pragma unroll
        for (int mt2 = 0; mt2 < 2; mt2++) {
            U4H8 aa;
            aa.u = f.aAt[mt2];
            accO[mt2] = __builtin_amdgcn_mfma_f32_16x16x32_f16(aa.h, bu.h, accO[mt2], 0, 0, 0);
            #pragma unroll
            for (int r = 0; r < 4; r++)
                o_out[ob + (long)(mt2 * 16 + quad * 4 + r) * DV + dv] = accO[mt2][r];
        }
        #pragma unroll
        for (int mt = 0; mt < 8; mt++) {
            U4H8 ak;
            ak.u = f.aK[mt];
            accS[mt] = __builtin_amdgcn_mfma_f32_16x16x32_f16(ak.h, bu.h, accS[mt], 0, 0, 0);
        }
    };

    Frags fA, fB;
    loadf(fA, 0);
    #pragma unroll 1
    for (int t = 0; t < GSZ; t += 2) {
        loadf(fB, t + 1);
        compute(fA, t);
        if (t + 2 < GSZ) loadf(fA, t + 2);
        compute(fB, t + 1);
    }
    // final S is written by phase3b.
}

extern "C" void kernel_launch(void* const* d_in, const int* in_sizes, int n_in,
                              void* d_out, int out_size, void* d_ws, size_t ws_size,
                              hipStream_t stream) {
    const float* q    = (const float*)d_in[0];
    const float* k    = (const float*)d_in[1];
    const float* v    = (const float*)d_in[2];
    const float* beta = (const float*)d_in[3];

    float* o = (float*)d_out;                      // [b,h,L,dv]
    float* S = o + (long)BH * LSEQ * DV;           // [b,h,dk,dv]

    const size_t nwq = (size_t)NBLK * 8 * 64;      // uint4 per A-frag file
    uint4* wnegf = (uint4*)d_ws;
    uint4* qnf = wnegf + nwq;
    uint4* ktf = qnf + nwq;
    uint4* atf = ktf + nwq;                        // NBLK*2*64 uint4
    uint2* uf  = (uint2*)(atf + (size_t)NBLK * 2 * 64);          // NBLK*16*64 uint2
    uint4* Pf  = (uint4*)(uf + (size_t)NBLK * 16 * 64);          // BH*NG*8*4*64 uint4
    uint2* Qgf = (uint2*)(Pf + (size_t)BH * NG * 8 * 4 * 64);    // BH*NG*8*8*64 uint2
    uint2* Sjf = Qgf + (size_t)BH * NG * 8 * 8 * 64;             // BH*16*8*8*64 uint2

    phase2_kernel<<<NBLK, 64, 0, stream>>>(q, k, v, beta, wnegf, qnf, ktf, atf, uf);
    phase3a_kernel<<<16 * 256, 64, 0, stream>>>(wnegf, ktf, uf, Pf, Qgf);
    phase3b_kernel<<<BH * 8, 256, 0, stream>>>(Pf, Qgf, Sjf, S);
    phase3c_kernel<<<8 * 256, 64, 0, stream>>>(wnegf, qnf, ktf, atf, uf, Sjf, o);
}

// Round 12
// 217.402 us; speedup vs baseline: 1.0766x; 1.0053x over previous
//
#include <hip/hip_runtime.h>
#include <hip/hip_bf16.h>

// DeltaNet chunkwise delta rule, b=2 h=8 L=4096 dk=dv=128 chunk=32.
// Phase2 (2048 wgs x 64 thr): r3 stream + neutral reg-double-buffer (r11).
//   55-56us floor proven across 7 variants (r4-r8, r11); not touched further.
// Phase3 = two-level scan over S' = (I - k^T w) S + k^T u, 16 groups x 8
//   chunks, XCD-L2 sharing via block swizzle (round-3).
//   Round-12: phase3a Q-scan and P-scan FUSED into one wave (grid 2048):
//   the two modes run identical step code with identical aW/aK inputs, so
//   one fA/fB pair feeds both chains (load traffic halved) and the two
//   independent dependency chains hide each other's per-step latency
//   (same mechanism as r9's proven 3b win). ~230 VGPR -> 2 waves/SIMD.
//   Phase3b (r9): 4-wave cooperative serial propagation (proven win).
//   Phase3c: r9 1-wave form (r10 2-wave split regressed).

#define B 2
#define H 8
#define LSEQ 4096
#define DK 128
#define DV 128
#define C 32
#define NCHUNK (LSEQ / C)      // 128
#define BH (B * H)             // 16
#define NBLK (BH * NCHUNK)     // 2048
#define NG 16                  // groups
#define GSZ 8                  // chunks per group (NG*GSZ == NCHUNK)

typedef _Float16 f16x8 __attribute__((ext_vector_type(8)));
typedef float f32x4 __attribute__((ext_vector_type(4)));

union U4H8 { uint4 u; f16x8 h; };

__device__ inline unsigned short f2h(float f) {
    _Float16 h = (_Float16)f;
    unsigned short u;
    __builtin_memcpy(&u, &h, 2);
    return u;
}
__device__ inline float h2f(unsigned int v) {
    unsigned short s = (unsigned short)v;
    _Float16 h;
    __builtin_memcpy(&h, &s, 2);
    return (float)h;
}
__device__ inline unsigned int pack2(float a, float b) {
    return (unsigned int)f2h(a) | ((unsigned int)f2h(b) << 16);
}
__device__ inline float dot4(float4 a, float4 b) {
    return a.x * b.x + a.y * b.y + a.z * b.z + a.w * b.w;
}
__device__ inline float bf16r(float x) {
    return __bfloat162float(__float2bfloat16(x));
}
__device__ inline uint2 pk4(float v0, float v1, float v2, float v3) {
    uint2 p; p.x = pack2(v0, v1); p.y = pack2(v2, v3); return p;
}
__device__ inline f32x4 up4(uint2 p) {
    f32x4 v;
    v[0] = h2f(p.x & 0xffffu); v[1] = h2f(p.x >> 16);
    v[2] = h2f(p.y & 0xffffu); v[3] = h2f(p.y >> 16);
    return v;
}

// ---------------- Phase 2 (r3 stream + neutral reg double-buffer) ----------------
#define S40 40
#define S136 136

__global__ __launch_bounds__(64) void phase2_kernel(
    const float* __restrict__ qg, const float* __restrict__ kg,
    const float* __restrict__ vg, const float* __restrict__ betag,
    uint4* __restrict__ wnegf, uint4* __restrict__ qnf,
    uint4* __restrict__ ktf, uint4* __restrict__ atf,
    uint2* __restrict__ uf)
{
    __shared__ alignas(16) _Float16 sA [32 * S40];
    __shared__ alignas(16) _Float16 sAT[32 * S40];
    __shared__ alignas(16) _Float16 sTT[32 * S40];
    __shared__ alignas(16) _Float16 sTB[32 * S40];
    __shared__ alignas(16) _Float16 sW [32 * S136];
    __shared__ alignas(16) float sbetaL[32];
    __shared__ alignas(16) float skscL[32];

    const int l = threadIdx.x;
    const int lm = l & 15, qd = l >> 4;
    const int blk = blockIdx.x;
    const long tb = (long)blk * C * DK;
    const f32x4 z4 = {0.f, 0.f, 0.f, 0.f};

    if (l < 32) sbetaL[l] = betag[(long)blk * C + l];

    U4H8 qF[8], kF[8];
    float ssq[2] = {0.f, 0.f}, ssk[2] = {0.f, 0.f};
    #pragma unroll
    for (int mt = 0; mt < 2; mt++) {
        #pragma unroll
        for (int kt = 0; kt < 4; kt++) {
            const float* qp = qg + tb + (long)(mt * 16 + lm) * DK + kt * 32 + qd * 8;
            const float* kp = kg + tb + (long)(mt * 16 + lm) * DK + kt * 32 + qd * 8;
            float4 a0 = *(const float4*)qp, a1 = *(const float4*)(qp + 4);
            float4 b0 = *(const float4*)kp, b1 = *(const float4*)(kp + 4);
            ssq[mt] += dot4(a0, a0) + dot4(a1, a1);
            ssk[mt] += dot4(b0, b0) + dot4(b1, b1);
            U4H8 x;
            x.u.x = pack2(a0.x, a0.y); x.u.y = pack2(a0.z, a0.w);
            x.u.z = pack2(a1.x, a1.y); x.u.w = pack2(a1.z, a1.w);
            qF[mt * 4 + kt] = x;
            U4H8 y;
            y.u.x = pack2(b0.x, b0.y); y.u.y = pack2(b0.z, b0.w);
            y.u.z = pack2(b1.x, b1.y); y.u.w = pack2(b1.z, b1.w);
            kF[mt * 4 + kt] = y;
        }
    }
    float qsc[2], ksc[2];
    #pragma unroll
    for (int mt = 0; mt < 2; mt++) {
        float s = ssq[mt];
        s += __shfl_xor(s, 16, 64);
        s += __shfl_xor(s, 32, 64);
        qsc[mt] = rsqrtf(s + 1e-6f);
        float t = ssk[mt];
        t += __shfl_xor(t, 16, 64);
        t += __shfl_xor(t, 32, 64);
        ksc[mt] = rsqrtf(t + 1e-6f);
    }
    if (qd == 0) { skscL[lm] = ksc[0]; skscL[16 + lm] = ksc[1]; }

    f32x4 alT[3] = {z4, z4, z4};
    #pragma unroll
    for (int kt = 0; kt < 4; kt++) {
        alT[0] = __builtin_amdgcn_mfma_f32_16x16x32_f16(kF[kt].h,     qF[kt].h,     alT[0], 0, 0, 0);
        alT[1] = __builtin_amdgcn_mfma_f32_16x16x32_f16(kF[kt].h,     qF[4 + kt].h, alT[1], 0, 0, 0);
        alT[2] = __builtin_amdgcn_mfma_f32_16x16x32_f16(kF[4 + kt].h, qF[4 + kt].h, alT[2], 0, 0, 0);
    }
    #pragma unroll
    for (int mt = 0; mt < 2; mt++) {
        _Float16 qs = (_Float16)qsc[mt];
        #pragma unroll
        for (int kt = 0; kt < 4; kt++) {
            U4H8 x;
            x.h = qF[mt * 4 + kt].h * qs;
            qnf[((long)blk * 8 + mt * 4 + kt) * 64 + l] = x.u;
        }
    }
    f32x4 rw[4] = {z4, z4, z4, z4};
    #pragma unroll
    for (int kt = 0; kt < 4; kt++) {
        rw[0] = __builtin_amdgcn_mfma_f32_16x16x32_f16(kF[kt].h,     kF[kt].h,     rw[0], 0, 0, 0);
        rw[1] = __builtin_amdgcn_mfma_f32_16x16x32_f16(kF[kt].h,     kF[4 + kt].h, rw[1], 0, 0, 0);
        rw[2] = __builtin_amdgcn_mfma_f32_16x16x32_f16(kF[4 + kt].h, kF[kt].h,     rw[2], 0, 0, 0);
        rw[3] = __builtin_amdgcn_mfma_f32_16x16x32_f16(kF[4 + kt].h, kF[4 + kt].h, rw[3], 0, 0, 0);
    }

    float4 b4[2], ks4[2];
    b4[0]  = *(const float4*)&sbetaL[qd * 4];      b4[1]  = *(const float4*)&sbetaL[16 + qd * 4];
    ks4[0] = *(const float4*)&skscL[qd * 4];       ks4[1] = *(const float4*)&skscL[16 + qd * 4];
    const float bcol0 = sbetaL[lm], bcol1 = sbetaL[16 + lm];

    {
        *(uint2*)&sTB[lm * S40 + 16 + qd * 4] = (uint2){0u, 0u};
        float v[4];
        #pragma unroll
        for (int r = 0; r < 4; r++) {
            int c = qd * 4 + r;
            v[r] = (c <= lm) ? (qsc[0] * (&ks4[0].x)[r] * alT[0][r]) : 0.f;
        }
        *(uint2*)&sTB[lm * S40 + qd * 4] = pk4(v[0], v[1], v[2], v[3]);
        #pragma unroll
        for (int r = 0; r < 4; r++) v[r] = qsc[1] * (&ks4[0].x)[r] * alT[1][r];
        *(uint2*)&sTB[(16 + lm) * S40 + qd * 4] = pk4(v[0], v[1], v[2], v[3]);
        #pragma unroll
        for (int r = 0; r < 4; r++) {
            int c = qd * 4 + r;
            v[r] = (c <= lm) ? (qsc[1] * (&ks4[1].x)[r] * alT[2][r]) : 0.f;
        }
        *(uint2*)&sTB[(16 + lm) * S40 + 16 + qd * 4] = pk4(v[0], v[1], v[2], v[3]);
    }
    #pragma unroll
    for (int f = 0; f < 2; f++) {
        uint4 x = *(const uint4*)&sTB[(f * 16 + lm) * S40 + qd * 8];
        atf[((long)blk * 2 + f) * 64 + l] = x;
    }

    {
        float v[4];
        *(uint2*)&sA [lm * S40 + 16 + qd * 4]        = (uint2){0u, 0u};
        *(uint2*)&sAT[(16 + lm) * S40 + qd * 4]      = (uint2){0u, 0u};
        *(uint2*)&sTT[(16 + lm) * S40 + qd * 4]      = (uint2){0u, 0u};
        #pragma unroll
        for (int r = 0; r < 4; r++) {
            int c = qd * 4 + r;
            v[r] = (c < lm) ? (-bcol0 * ksc[0] * (&ks4[0].x)[r] * rw[0][r]) : 0.f;
        }
        *(uint2*)&sA[lm * S40 + qd * 4] = pk4(v[0], v[1], v[2], v[3]);
        #pragma unroll
        for (int r = 0; r < 4; r++) v[r] = -bcol1 * ksc[1] * (&ks4[0].x)[r] * rw[1][r];
        *(uint2*)&sA[(16 + lm) * S40 + qd * 4] = pk4(v[0], v[1], v[2], v[3]);
        #pragma unroll
        for (int r = 0; r < 4; r++) {
            int c = qd * 4 + r;
            v[r] = (c < lm) ? (-bcol1 * ksc[1] * (&ks4[1].x)[r] * rw[3][r]) : 0.f;
        }
        *(uint2*)&sA[(16 + lm) * S40 + 16 + qd * 4] = pk4(v[0], v[1], v[2], v[3]);
        #pragma unroll
        for (int r = 0; r < 4; r++) {
            int c = qd * 4 + r;
            v[r] = (c > lm) ? (-(&b4[0].x)[r] * (&ks4[0].x)[r] * ksc[0] * rw[0][r]) : 0.f;
        }
        *(uint2*)&sAT[lm * S40 + qd * 4] = pk4(v[0], v[1], v[2], v[3]);
        #pragma unroll
        for (int r = 0; r < 4; r++) v[r] = -(&b4[1].x)[r] * (&ks4[1].x)[r] * ksc[0] * rw[2][r];
        *(uint2*)&sAT[lm * S40 + 16 + qd * 4] = pk4(v[0], v[1], v[2], v[3]);
        #pragma unroll
        for (int r = 0; r < 4; r++) {
            int c = qd * 4 + r;
            v[r] = (c > lm) ? (-(&b4[1].x)[r] * (&ks4[1].x)[r] * ksc[1] * rw[3][r]) : 0.f;
        }
        *(uint2*)&sAT[(16 + lm) * S40 + 16 + qd * 4] = pk4(v[0], v[1], v[2], v[3]);
        #pragma unroll
        for (int r = 0; r < 4; r++) {
            int c = qd * 4 + r;
            v[r] = (c > lm) ? (-(&b4[0].x)[r] * (&ks4[0].x)[r] * ksc[0] * rw[0][r])
                            : ((c == lm) ? 1.0f : 0.f);
        }
        *(uint2*)&sTT[lm * S40 + qd * 4] = pk4(v[0], v[1], v[2], v[3]);
        #pragma unroll
        for (int r = 0; r < 4; r++) v[r] = -(&b4[1].x)[r] * (&ks4[1].x)[r] * ksc[0] * rw[2][r];
        *(uint2*)&sTT[lm * S40 + 16 + qd * 4] = pk4(v[0], v[1], v[2], v[3]);
        #pragma unroll
        for (int r = 0; r < 4; r++) {
            int c = qd * 4 + r;
            v[r] = (c > lm) ? (-(&b4[1].x)[r] * (&ks4[1].x)[r] * ksc[1] * rw[3][r])
                            : ((c == lm) ? 1.0f : 0.f);
        }
        *(uint2*)&sTT[(16 + lm) * S40 + 16 + qd * 4] = pk4(v[0], v[1], v[2], v[3]);
    }
    f32x4 Tc[3], TTc[3];
    #pragma unroll
    for (int r = 0; r < 4; r++) {
        int rr = qd * 4 + r;
        Tc[0][r] = (lm < rr) ? (-(&b4[0].x)[r] * (&ks4[0].x)[r] * ksc[0] * rw[0][r])
                             : ((lm == rr) ? 1.0f : 0.f);
        Tc[1][r] = -(&b4[1].x)[r] * (&ks4[1].x)[r] * ksc[0] * rw[2][r];
        Tc[2][r] = (lm < rr) ? (-(&b4[1].x)[r] * (&ks4[1].x)[r] * ksc[1] * rw[3][r])
                             : ((lm == rr) ? 1.0f : 0.f);
        TTc[0][r] = (rr < lm) ? (-bcol0 * ksc[0] * (&ks4[0].x)[r] * rw[0][r])
                              : ((rr == lm) ? 1.0f : 0.f);
        TTc[1][r] = -bcol1 * ksc[1] * (&ks4[0].x)[r] * rw[1][r];
        TTc[2][r] = (rr < lm) ? (-bcol1 * ksc[1] * (&ks4[1].x)[r] * rw[3][r])
                              : ((rr == lm) ? 1.0f : 0.f);
    }

    #pragma unroll
    for (int p = 0; p < 4; p++) {
        U4H8 AF[2], ATF[2], TTF[2];
        AF[0].u  = *(const uint4*)&sA [lm * S40 + qd * 8];
        AF[1].u  = *(const uint4*)&sA [(16 + lm) * S40 + qd * 8];
        ATF[0].u = *(const uint4*)&sAT[lm * S40 + qd * 8];
        ATF[1].u = *(const uint4*)&sAT[(16 + lm) * S40 + qd * 8];
        TTF[0].u = *(const uint4*)&sTT[lm * S40 + qd * 8];
        TTF[1].u = *(const uint4*)&sTT[(16 + lm) * S40 + qd * 8];

        f32x4 A2_00 = __builtin_amdgcn_mfma_f32_16x16x32_f16(AF[0].h, ATF[0].h, z4, 0, 0, 0);
        f32x4 A2_10 = __builtin_amdgcn_mfma_f32_16x16x32_f16(AF[1].h, ATF[0].h, z4, 0, 0, 0);
        f32x4 A2_11 = __builtin_amdgcn_mfma_f32_16x16x32_f16(AF[1].h, ATF[1].h, z4, 0, 0, 0);
        f32x4 A2T_00 = __builtin_amdgcn_mfma_f32_16x16x32_f16(ATF[0].h, AF[0].h, z4, 0, 0, 0);
        f32x4 A2T_01 = __builtin_amdgcn_mfma_f32_16x16x32_f16(ATF[0].h, AF[1].h, z4, 0, 0, 0);
        f32x4 A2T_11 = __builtin_amdgcn_mfma_f32_16x16x32_f16(ATF[1].h, AF[1].h, z4, 0, 0, 0);

        {
            float v[4];
            #pragma unroll
            for (int r = 0; r < 4; r++) { int c = qd * 4 + r; v[r] = (c < lm) ? A2T_00[r] : 0.f; }
            *(uint2*)&sA[lm * S40 + qd * 4] = pk4(v[0], v[1], v[2], v[3]);
            *(uint2*)&sA[(16 + lm) * S40 + qd * 4] = pk4(A2T_01[0], A2T_01[1], A2T_01[2], A2T_01[3]);
            #pragma unroll
            for (int r = 0; r < 4; r++) { int c = qd * 4 + r; v[r] = (c < lm) ? A2T_11[r] : 0.f; }
            *(uint2*)&sA[(16 + lm) * S40 + 16 + qd * 4] = pk4(v[0], v[1], v[2], v[3]);
        }
        if (p < 3) {
            float v[4];
            #pragma unroll
            for (int r = 0; r < 4; r++) { int c = qd * 4 + r; v[r] = (c > lm) ? A2_00[r] : 0.f; }
            *(uint2*)&sAT[lm * S40 + qd * 4] = pk4(v[0], v[1], v[2], v[3]);
            *(uint2*)&sAT[lm * S40 + 16 + qd * 4] = pk4(A2_10[0], A2_10[1], A2_10[2], A2_10[3]);
            #pragma unroll
            for (int r = 0; r < 4; r++) { int c = qd * 4 + r; v[r] = (c > lm) ? A2_11[r] : 0.f; }
            *(uint2*)&sAT[(16 + lm) * S40 + 16 + qd * 4] = pk4(v[0], v[1], v[2], v[3]);
        }
        U4H8 AnF[2];
        AnF[0].u = *(const uint4*)&sA[lm * S40 + qd * 8];
        AnF[1].u = *(const uint4*)&sA[(16 + lm) * S40 + qd * 8];
        Tc[0]  = __builtin_amdgcn_mfma_f32_16x16x32_f16(AnF[0].h, TTF[0].h, Tc[0], 0, 0, 0);
        Tc[1]  = __builtin_amdgcn_mfma_f32_16x16x32_f16(AnF[1].h, TTF[0].h, Tc[1], 0, 0, 0);
        Tc[2]  = __builtin_amdgcn_mfma_f32_16x16x32_f16(AnF[1].h, TTF[1].h, Tc[2], 0, 0, 0);
        TTc[0] = __builtin_amdgcn_mfma_f32_16x16x32_f16(TTF[0].h, AnF[0].h, TTc[0], 0, 0, 0);
        TTc[1] = __builtin_amdgcn_mfma_f32_16x16x32_f16(TTF[0].h, AnF[1].h, TTc[1], 0, 0, 0);
        TTc[2] = __builtin_amdgcn_mfma_f32_16x16x32_f16(TTF[1].h, AnF[1].h, TTc[2], 0, 0, 0);
        if (p < 3) {
            *(uint2*)&sTT[lm * S40 + qd * 4]             = pk4(Tc[0][0], Tc[0][1], Tc[0][2], Tc[0][3]);
            *(uint2*)&sTT[lm * S40 + 16 + qd * 4]        = pk4(Tc[1][0], Tc[1][1], Tc[1][2], Tc[1][3]);
            *(uint2*)&sTT[(16 + lm) * S40 + 16 + qd * 4] = pk4(Tc[2][0], Tc[2][1], Tc[2][2], Tc[2][3]);
        }
    }

    {
        *(uint2*)&sTB[lm * S40 + 16 + qd * 4] = (uint2){0u, 0u};
        float v[4];
        #pragma unroll
        for (int r = 0; r < 4; r++) v[r] = bf16r(TTc[0][r]) * (&b4[0].x)[r];
        *(uint2*)&sTB[lm * S40 + qd * 4] = pk4(v[0], v[1], v[2], v[3]);
        #pragma unroll
        for (int r = 0; r < 4; r++) v[r] = bf16r(TTc[1][r]) * (&b4[0].x)[r];
        *(uint2*)&sTB[(16 + lm) * S40 + qd * 4] = pk4(v[0], v[1], v[2], v[3]);
        #pragma unroll
        for (int r = 0; r < 4; r++) v[r] = bf16r(TTc[2][r]) * (&b4[1].x)[r];
        *(uint2*)&sTB[(16 + lm) * S40 + 16 + qd * 4] = pk4(v[0], v[1], v[2], v[3]);
    }
    U4H8 TbF[2];
    TbF[0].u = *(const uint4*)&sTB[lm * S40 + qd * 8];
    TbF[1].u = *(const uint4*)&sTB[(16 + lm) * S40 + qd * 8];

    float kscj[8];
    #pragma unroll
    for (int j = 0; j < 8; j++) kscj[j] = skscL[qd * 8 + j];
    float vbuf[2][8], kbuf[2][8];
    #pragma unroll
    for (int j = 0; j < 8; j++) {
        const long ro = tb + (long)(qd * 8 + j) * DK + lm;
        vbuf[0][j] = vg[ro];
        kbuf[0][j] = kg[ro];
    }
    #pragma unroll
    for (int nt = 0; nt < 8; nt++) {
        const int cur = nt & 1, nxt = cur ^ 1;
        if (nt < 7) {
            #pragma unroll
            for (int j = 0; j < 8; j++) {
                const long ro = tb + (long)(qd * 8 + j) * DK + (nt + 1) * 16 + lm;
                vbuf[nxt][j] = vg[ro];
                kbuf[nxt][j] = kg[ro];
            }
        }
        U4H8 bV, bK;
        #pragma unroll
        for (int j = 0; j < 8; j++) {
            bV.h[j] = (_Float16)vbuf[cur][j];
            bK.h[j] = (_Float16)(kbuf[cur][j] * kscj[j]);
        }
        ktf[((long)blk * 8 + nt) * 64 + l] = bK.u;
        f32x4 u0 = __builtin_amdgcn_mfma_f32_16x16x32_f16(TbF[0].h, bV.h, z4, 0, 0, 0);
        f32x4 u1 = __builtin_amdgcn_mfma_f32_16x16x32_f16(TbF[1].h, bV.h, z4, 0, 0, 0);
        uf[(((long)blk * 2 + 0) * 8 + nt) * 64 + l] = pk4(u0[0], u0[1], u0[2], u0[3]);
        uf[(((long)blk * 2 + 1) * 8 + nt) * 64 + l] = pk4(u1[0], u1[1], u1[2], u1[3]);
        f32x4 w0 = __builtin_amdgcn_mfma_f32_16x16x32_f16(TbF[0].h, bK.h, z4, 0, 0, 0);
        f32x4 w1 = __builtin_amdgcn_mfma_f32_16x16x32_f16(TbF[1].h, bK.h, z4, 0, 0, 0);
        #pragma unroll
        for (int r = 0; r < 4; r++) {
            sW[(qd * 4 + r) * S136 + nt * 16 + lm]        = (_Float16)(-w0[r]);
            sW[(16 + qd * 4 + r) * S136 + nt * 16 + lm]   = (_Float16)(-w1[r]);
        }
    }
    #pragma unroll
    for (int mt2 = 0; mt2 < 2; mt2++) {
        #pragma unroll
        for (int kt = 0; kt < 4; kt++) {
            uint4 x = *(const uint4*)&sW[(mt2 * 16 + lm) * S136 + kt * 32 + qd * 8];
            wnegf[((long)blk * 8 + mt2 * 4 + kt) * 64 + l] = x;
        }
    }
}

// ---------------- Phase 3a: FUSED Q+P scan, one wave per (w, bh, grp) ----------------
// grid = 8*256: blockIdx = w*256 + g, g = bh*16+grp. All 8 sharers of one g
// have idx%8 == g%8 -> same XCD L2. Each wave runs BOTH the Q-chain (u-scan
// from 0) and the P-chain (identity stripes) off ONE fA/fB frag pair: load
// traffic halved, and the two independent chains hide each other's per-step
// LDS->MFMA latency. Per-element MFMA order identical to the split version.
__global__ __launch_bounds__(64, 1) void phase3a_kernel(
    const uint4* __restrict__ wnegf, const uint4* __restrict__ ktf,
    const uint2* __restrict__ uf,
    uint4* __restrict__ Pf, uint2* __restrict__ Qgf)
{
    __shared__ alignas(16) _Float16 S16Q[16 * 16 * 8];
    __shared__ alignas(16) _Float16 S16P[16 * 16 * 8];
    __shared__ alignas(16) _Float16 U16Q[4 * 16 * 8];
    __shared__ alignas(16) _Float16 U16P[4 * 16 * 8];
    __shared__ alignas(16) _Float16 PT[128 * 16];

    const int l = threadIdx.x;
    const int lm = l & 15, quad = l >> 4;
    const int idx = blockIdx.x;
    const int w = idx >> 8;
    const int g = idx & 255;             // bh*16+grp
    const int bh = g >> 4;
    const int grp = g & 15;
    const f32x4 z4 = {0.f, 0.f, 0.f, 0.f};

    f32x4 accQ[8], accP[8];
    #pragma unroll
    for (int mt = 0; mt < 8; mt++) {
        accQ[mt] = z4;
        #pragma unroll
        for (int r = 0; r < 4; r++)
            accP[mt][r] = (mt == w && quad * 4 + r == lm) ? 1.f : 0.f;
    }

    struct FragA { uint4 aW[2][4]; uint4 aK[8]; uint2 aU[2]; };
    FragA fA, fB;

    auto loadf = [&](FragA& f, int t) {
        const long blk = (long)bh * NCHUNK + grp * GSZ + t;
        #pragma unroll
        for (int mt2 = 0; mt2 < 2; mt2++)
            #pragma unroll
            for (int kt = 0; kt < 4; kt++)
                f.aW[mt2][kt] = wnegf[(blk * 8 + mt2 * 4 + kt) * 64 + l];
        #pragma unroll
        for (int mt = 0; mt < 8; mt++) f.aK[mt] = ktf[(blk * 8 + mt) * 64 + l];
        #pragma unroll
        for (int mt2 = 0; mt2 < 2; mt2++)
            f.aU[mt2] = uf[((blk * 2 + mt2) * 8 + w) * 64 + l];
    };

    auto compute = [&](const FragA& f) {
        // Stage A: both accumulators -> their S16 buffers
        #pragma unroll
        for (int mt = 0; mt < 8; mt++) {
            int g2 = 2 * mt + (quad >> 1);
            int sub = (quad & 1) * 4;
            *(uint2*)&S16Q[(g2 * 16 + lm) * 8 + sub] =
                pk4(accQ[mt][0], accQ[mt][1], accQ[mt][2], accQ[mt][3]);
            *(uint2*)&S16P[(g2 * 16 + lm) * 8 + sub] =
                pk4(accP[mt][0], accP[mt][1], accP[mt][2], accP[mt][3]);
        }
        // Stage B: two independent chains share aW
        f32x4 accUQ[2], accUP[2];
        #pragma unroll
        for (int mt2 = 0; mt2 < 2; mt2++) {
            accUQ[mt2] = up4(f.aU[mt2]);
            accUP[mt2] = z4;
        }
        #pragma unroll
        for (int kt = 0; kt < 4; kt++) {
            U4H8 bsQ, bsP;
            bsQ.u = *(const uint4*)&S16Q[((kt * 4 + quad) * 16 + lm) * 8];
            bsP.u = *(const uint4*)&S16P[((kt * 4 + quad) * 16 + lm) * 8];
            #pragma unroll
            for (int mt2 = 0; mt2 < 2; mt2++) {
                U4H8 aw; aw.u = f.aW[mt2][kt];
                accUQ[mt2] = __builtin_amdgcn_mfma_f32_16x16x32_f16(aw.h, bsQ.h, accUQ[mt2], 0, 0, 0);
                accUP[mt2] = __builtin_amdgcn_mfma_f32_16x16x32_f16(aw.h, bsP.h, accUP[mt2], 0, 0, 0);
            }
        }
        // Stage C: both u_new tiles -> U16 buffers
        #pragma unroll
        for (int mt2 = 0; mt2 < 2; mt2++) {
            int g2 = 2 * mt2 + (quad >> 1);
            int sub = (quad & 1) * 4;
            *(uint2*)&U16Q[(g2 * 16 + lm) * 8 + sub] =
                pk4(accUQ[mt2][0], accUQ[mt2][1], accUQ[mt2][2], accUQ[mt2][3]);
            *(uint2*)&U16P[(g2 * 16 + lm) * 8 + sub] =
                pk4(accUP[mt2][0], accUP[mt2][1], accUP[mt2][2], accUP[mt2][3]);
        }
        U4H8 buQ, buP;
        buQ.u = *(const uint4*)&U16Q[(quad * 16 + lm) * 8];
        buP.u = *(const uint4*)&U16P[(quad * 16 + lm) * 8];
        // Stage E: both chains share aK
        #pragma unroll
        for (int mt = 0; mt < 8; mt++) {
            U4H8 ak; ak.u = f.aK[mt];
            accQ[mt] = __builtin_amdgcn_mfma_f32_16x16x32_f16(ak.h, buQ.h, accQ[mt], 0, 0, 0);
            accP[mt] = __builtin_amdgcn_mfma_f32_16x16x32_f16(ak.h, buP.h, accP[mt], 0, 0, 0);
        }
    };

    loadf(fA, 0);
    #pragma unroll 1
    for (int t = 0; t < GSZ; t += 2) {
        loadf(fB, t + 1);
        compute(fA);
        if (t + 2 < GSZ) loadf(fA, t + 2);
        compute(fB);
    }

    // Q_g: packed fp16 C-frags
    {
        const long qb = (((long)(bh * NG + grp)) * 8 + w) * 8 * 64;
        #pragma unroll
        for (int mt = 0; mt < 8; mt++)
            Qgf[qb + mt * 64 + l] = pk4(accQ[mt][0], accQ[mt][1], accQ[mt][2], accQ[mt][3]);
    }
    // P_g column-stripe -> LDS row-major [128][16] -> A-frag halves.
    // grp 0's P is never read (S_0 = 0); skip its store.
    if (grp != 0) {
        #pragma unroll
        for (int mt = 0; mt < 8; mt++)
            #pragma unroll
            for (int r = 0; r < 4; r++)
                PT[(mt * 16 + quad * 4 + r) * 16 + lm] = (_Float16)accP[mt][r];
        const int tl = ((w & 1) << 5) | (l & 31);
        const int half = l >> 5;
        const long pb = ((long)(bh * NG + grp)) * 8;
        #pragma unroll
        for (int i = 0; i < 4; i++) {
            int mt = half * 4 + i;
            uint4 x = *(const uint4*)&PT[(mt * 16 + (tl & 15)) * 16 + ((tl >> 4) & 1) * 8];
            Pf[((pb + mt) * 4 + (w >> 1)) * 64 + tl] = x;
        }
    }
}

// ---------------- Phase 3b: 4-wave serial group-state propagation (r9) ----------------
__global__ __launch_bounds__(256, 1) void phase3b_kernel(
    const uint4* __restrict__ Pf, const uint2* __restrict__ Qgf,
    uint2* __restrict__ Sjf, float* __restrict__ S_out)
{
    __shared__ alignas(16) _Float16 S16[2][16 * 16 * 8];

    const int tid = threadIdx.x;
    const int l = tid & 63;
    const int ww = tid >> 6;             // wave 0..3
    const int lm = l & 15, quad = l >> 4;
    const int bh = blockIdx.x & 15;
    const int w = blockIdx.x >> 4;

    f32x4 accS[2];
    #pragma unroll
    for (int i = 0; i < 2; i++) accS[i] = (f32x4){0.f, 0.f, 0.f, 0.f};

    uint2 Q0[2], Q1[2];
    uint4 P0[2][4], P1[2][4];

    auto loadQ = [&](uint2 (&Q)[2], int j) {
        const long b = (((long)(bh * NG + j)) * 8 + w) * 8 * 64;
        #pragma unroll
        for (int i = 0; i < 2; i++) Q[i] = Qgf[b + (ww * 2 + i) * 64 + l];
    };
    auto loadP = [&](uint4 (&P)[2][4], int j) {
        const long b = ((long)(bh * NG + j)) * 8;
        #pragma unroll
        for (int i = 0; i < 2; i++)
            #pragma unroll
            for (int kt = 0; kt < 4; kt++)
                P[i][kt] = Pf[((b + ww * 2 + i) * 4 + kt) * 64 + l];
    };
    auto computeB = [&](int j, const uint2 (&Q)[2], const uint4 (&P)[2][4]) {
        f32x4 ns[2];
        #pragma unroll
        for (int i = 0; i < 2; i++) ns[i] = up4(Q[i]);
        if (j) {
            const int buf = j & 1;
            #pragma unroll
            for (int i = 0; i < 2; i++) {
                int mt = ww * 2 + i;
                int g2 = 2 * mt + (quad >> 1);
                int sub = (quad & 1) * 4;
                *(uint2*)&S16[buf][(g2 * 16 + lm) * 8 + sub] =
                    pk4(accS[i][0], accS[i][1], accS[i][2], accS[i][3]);
            }
            __syncthreads();
            #pragma unroll
            for (int kt = 0; kt < 4; kt++) {
                U4H8 bs;
                bs.u = *(const uint4*)&S16[buf][((kt * 4 + quad) * 16 + lm) * 8];
                #pragma unroll
                for (int i = 0; i < 2; i++) {
                    U4H8 ap; ap.u = P[i][kt];
                    ns[i] = __builtin_amdgcn_mfma_f32_16x16x32_f16(ap.h, bs.h, ns[i], 0, 0, 0);
                }
            }
        }
        #pragma unroll
        for (int i = 0; i < 2; i++) accS[i] = ns[i];
        if (j < 15) {
            const long sb = (((long)(bh * 16 + (j + 1))) * 8 + w) * 8 * 64;
            #pragma unroll
            for (int i = 0; i < 2; i++)
                Sjf[sb + (ww * 2 + i) * 64 + l] = pk4(ns[i][0], ns[i][1], ns[i][2], ns[i][3]);
        } else {
            #pragma unroll
            for (int i = 0; i < 2; i++) {
                int mt = ww * 2 + i;
                #pragma unroll
                for (int r = 0; r < 4; r++)
                    S_out[(long)bh * (DK * DV) + (long)(mt * 16 + quad * 4 + r) * DV + w * 16 + lm] = ns[i][r];
            }
        }
    };

    loadQ(Q0, 0);
    loadP(P1, 1);
    #pragma unroll 1
    for (int j = 0; j < 16; j += 2) {
        loadQ(Q1, j + 1);
        computeB(j, Q0, P0);
        if (j + 2 < 16) { loadP(P0, j + 2); loadQ(Q0, j + 2); }
        computeB(j + 1, Q1, P1);
        if (j + 3 < 16) loadP(P1, j + 3);
    }
}

// ---------------- Phase 3c: 1-wave group replay (r9), emit o ----------------
struct Frags {
    uint4 aW[2][4];
    uint4 aQ[2][4];
    uint4 aK[8];
    uint4 aAt[2];
    uint2 aU[2];
};

__global__ __launch_bounds__(64, 1) void phase3c_kernel(
    const uint4* __restrict__ wnegf, const uint4* __restrict__ qnf,
    const uint4* __restrict__ ktf, const uint4* __restrict__ atf,
    const uint2* __restrict__ uf, const uint2* __restrict__ Sjf,
    float* __restrict__ o_out)
{
    __shared__ alignas(16) _Float16 S16[16 * 16 * 8];  // 4KB
    __shared__ alignas(16) _Float16 U16[4 * 16 * 8];   // 1KB

    const int l = threadIdx.x;
    const int lm = l & 15, quad = l >> 4;
    const int idx = blockIdx.x;
    const int w = idx >> 8;
    const int g = idx & 255;
    const int bh = g >> 4;
    const int grp = g & 15;
    const int dv = w * 16 + lm;

    f32x4 accS[8];
    if (grp == 0) {
        #pragma unroll
        for (int mt = 0; mt < 8; mt++) accS[mt] = (f32x4){0.f, 0.f, 0.f, 0.f};
    } else {
        const long sb = (((long)(bh * 16 + grp)) * 8 + w) * 8 * 64;
        #pragma unroll
        for (int mt = 0; mt < 8; mt++) accS[mt] = up4(Sjf[sb + mt * 64 + l]);
    }

    auto loadf = [&](Frags& f, int t) {
        const long blk = (long)bh * NCHUNK + grp * GSZ + t;
        #pragma unroll
        for (int mt2 = 0; mt2 < 2; mt2++) {
            #pragma unroll
            for (int kt = 0; kt < 4; kt++) {
                f.aW[mt2][kt] = wnegf[(blk * 8 + mt2 * 4 + kt) * 64 + l];
                f.aQ[mt2][kt] = qnf[(blk * 8 + mt2 * 4 + kt) * 64 + l];
            }
            f.aAt[mt2] = atf[(blk * 2 + mt2) * 64 + l];
            f.aU[mt2] = uf[((blk * 2 + mt2) * 8 + w) * 64 + l];
        }
        #pragma unroll
        for (int mt = 0; mt < 8; mt++) f.aK[mt] = ktf[(blk * 8 + mt) * 64 + l];
    };

    auto compute = [&](const Frags& f, int t) {
        #pragma unroll
        for (int mt = 0; mt < 8; mt++) {
            int g2 = 2 * mt + (quad >> 1);
            int sub = (quad & 1) * 4;
            *(uint2*)&S16[(g2 * 16 + lm) * 8 + sub] =
                pk4(accS[mt][0], accS[mt][1], accS[mt][2], accS[mt][3]);
        }
        f32x4 accU[2], accO[2];
        #pragma unroll
        for (int mt2 = 0; mt2 < 2; mt2++) {
            accU[mt2] = up4(f.aU[mt2]);
            accO[mt2] = (f32x4){0.f, 0.f, 0.f, 0.f};
        }
        #pragma unroll
        for (int kt = 0; kt < 4; kt++) {
            U4H8 bs;
            bs.u = *(const uint4*)&S16[((kt * 4 + quad) * 16 + lm) * 8];
            #pragma unroll
            for (int mt2 = 0; mt2 < 2; mt2++) {
                U4H8 aw, aq;
                aw.u = f.aW[mt2][kt];
                aq.u = f.aQ[mt2][kt];
                accU[mt2] = __builtin_amdgcn_mfma_f32_16x16x32_f16(aw.h, bs.h, accU[mt2], 0, 0, 0);
                accO[mt2] = __builtin_amdgcn_mfma_f32_16x16x32_f16(aq.h, bs.h, accO[mt2], 0, 0, 0);
            }
        }
        #pragma unroll
        for (int mt2 = 0; mt2 < 2; mt2++) {
            int g2 = 2 * mt2 + (quad >> 1);
            int sub = (quad & 1) * 4;
            *(uint2*)&U16[(g2 * 16 + lm) * 8 + sub] =
                pk4(accU[mt2][0], accU[mt2][1], accU[mt2][2], accU[mt2][3]);
        }
        U4H8 bu;
        bu.u = *(const uint4*)&U16[(quad * 16 + lm) * 8];
        const long ob = ((long)bh * LSEQ + (long)(grp * GSZ + t) * C) * DV;
        #pragma unroll
        for (int mt2 = 0; mt2 < 2; mt2++) {
            U4H8 aa;
            aa.u = f.aAt[mt2];
            accO[mt2] = __builtin_amdgcn_mfma_f32_16x16x32_f16(aa.h, bu.h, accO[mt2], 0, 0, 0);
            #pragma unroll
            for (int r = 0; r < 4; r++)
                o_out[ob + (long)(mt2 * 16 + quad * 4 + r) * DV + dv] = accO[mt2][r];
        }
        #pragma unroll
        for (int mt = 0; mt < 8; mt++) {
            U4H8 ak;
            ak.u = f.aK[mt];
            accS[mt] = __builtin_amdgcn_mfma_f32_16x16x32_f16(ak.h, bu.h, accS[mt], 0, 0, 0);
        }
    };

    Frags fA, fB;
    loadf(fA, 0);
    #pragma unroll 1
    for (int t = 0; t < GSZ; t += 2) {
        loadf(fB, t + 1);
        compute(fA, t);
        if (t + 2 < GSZ) loadf(fA, t + 2);
        compute(fB, t + 1);
    }
    // final S is written by phase3b.
}

extern "C" void kernel_launch(void* const* d_in, const int* in_sizes, int n_in,
                              void* d_out, int out_size, void* d_ws, size_t ws_size,
                              hipStream_t stream) {
    const float* q    = (const float*)d_in[0];
    const float* k    = (const float*)d_in[1];
    const float* v    = (const float*)d_in[2];
    const float* beta = (const float*)d_in[3];

    float* o = (float*)d_out;                      // [b,h,L,dv]
    float* S = o + (long)BH * LSEQ * DV;           // [b,h,dk,dv]

    const size_t nwq = (size_t)NBLK * 8 * 64;      // uint4 per A-frag file
    uint4* wnegf = (uint4*)d_ws;
    uint4* qnf = wnegf + nwq;
    uint4* ktf = qnf + nwq;
    uint4* atf = ktf + nwq;                        // NBLK*2*64 uint4
    uint2* uf  = (uint2*)(atf + (size_t)NBLK * 2 * 64);          // NBLK*16*64 uint2
    uint4* Pf  = (uint4*)(uf + (size_t)NBLK * 16 * 64);          // BH*NG*8*4*64 uint4
    uint2* Qgf = (uint2*)(Pf + (size_t)BH * NG * 8 * 4 * 64);    // BH*NG*8*8*64 uint2
    uint2* Sjf = Qgf + (size_t)BH * NG * 8 * 8 * 64;             // BH*16*8*8*64 uint2

    phase2_kernel<<<NBLK, 64, 0, stream>>>(q, k, v, beta, wnegf, qnf, ktf, atf, uf);
    phase3a_kernel<<<8 * 256, 64, 0, stream>>>(wnegf, ktf, uf, Pf, Qgf);
    phase3b_kernel<<<BH * 8, 256, 0, stream>>>(Pf, Qgf, Sjf, S);
    phase3c_kernel<<<8 * 256, 64, 0, stream>>>(wnegf, qnf, ktf, atf, uf, Sjf, o);
}